// Round 1
// baseline (452.867 us; speedup 1.0000x reference)
//
#include <hip/hip_runtime.h>
#include <math.h>

#define F0 136
#define F1 68
#define F2 6

// ---------------- init: deg=1 (self loop), pool=0 ----------------
__global__ void k_init(float* __restrict__ deg, float* __restrict__ pool, int N, int G) {
    int i = blockIdx.x * blockDim.x + threadIdx.x;
    if (i < N) deg[i] = 1.0f;
    if (i < G) pool[i] = 0.0f;
}

// ---------------- degree count over edge destinations ----------------
__global__ void k_degcount(const int* __restrict__ dst, float* __restrict__ deg, int E) {
    int e = blockIdx.x * blockDim.x + threadIdx.x;
    if (e < E) atomicAdd(&deg[dst[e]], 1.0f);
}

// ---------------- dinv = rsqrt(deg), in place ----------------
__global__ void k_rsqrt(float* __restrict__ deg, int N) {
    int i = blockIdx.x * blockDim.x + threadIdx.x;
    if (i < N) deg[i] = rsqrtf(deg[i]);
}

// ---------------- per-edge norm = dinv[src]*dinv[dst] ----------------
__global__ void k_norm(const int* __restrict__ src, const int* __restrict__ dst,
                       const float* __restrict__ dinv, float* __restrict__ nrm, int E) {
    int e = blockIdx.x * blockDim.x + threadIdx.x;
    if (e < E) nrm[e] = dinv[src[e]] * dinv[dst[e]];
}

// ---------------- lin1: h1 = x @ W1 ; agg1 = h1 * dinv^2 (self-loop init) ----
// 256 threads, 64 nodes/block, 4 threads per node (17 cols each).
// W1 staged in LDS col-major [c][k] for conflict-free ds_read_b128.
__global__ __launch_bounds__(256) void k_lin1(const float* __restrict__ x,
                                              const float* __restrict__ W1,
                                              const float* __restrict__ dinv,
                                              float* __restrict__ h1,
                                              float* __restrict__ agg1, int N) {
    __shared__ float sw[F1 * F0];  // 68*136 floats = 37 KB, col-major [c][k]
    int tid = threadIdx.x;
    for (int i = tid; i < F0 * F1; i += 256) {
        int k = i / F1, c = i - k * F1;
        sw[c * F0 + k] = W1[i];
    }
    __syncthreads();

    int local = tid >> 2;            // node within block: 0..63
    int cq    = tid & 3;             // column quarter
    int c0    = cq * 17;
    int node  = blockIdx.x * 64 + local;
    if (node >= N) return;

    float acc[17];
#pragma unroll
    for (int j = 0; j < 17; j++) acc[j] = 0.0f;

    const float* xrow = x + (size_t)node * F0;
    for (int k = 0; k < F0; k += 4) {
        float4 xv = *(const float4*)&xrow[k];
#pragma unroll
        for (int j = 0; j < 17; j++) {
            float4 wv = *(const float4*)&sw[(c0 + j) * F0 + k];
            acc[j] += xv.x * wv.x + xv.y * wv.y + xv.z * wv.z + xv.w * wv.w;
        }
    }
    float d = dinv[node];
    float d2 = d * d;
    float* hrow = h1 + (size_t)node * F1 + c0;
    float* arow = agg1 + (size_t)node * F1 + c0;
#pragma unroll
    for (int j = 0; j < 17; j++) {
        float v = acc[j];
        hrow[j] = v;
        arow[j] = v * d2;
    }
}

// ---------------- agg1 edge scatter: agg1[dst] += h1[src]*norm -------------
// one wave (64 lanes) per edge; lanes cover 68 cols (4 lanes do 2 cols)
__global__ __launch_bounds__(256) void k_agg1(const int* __restrict__ src,
                                              const int* __restrict__ dst,
                                              const float* __restrict__ nrm,
                                              const float* __restrict__ h1,
                                              float* __restrict__ agg1, int E) {
    int lane = threadIdx.x & 63;
    int e = blockIdx.x * 4 + (threadIdx.x >> 6);
    if (e >= E) return;
    int s = src[e], d = dst[e];
    float w = nrm[e];
    const float* hs = h1 + (size_t)s * F1;
    float* ad = agg1 + (size_t)d * F1;
    atomicAdd(&ad[lane], hs[lane] * w);
    if (lane < F1 - 64) atomicAdd(&ad[64 + lane], hs[64 + lane] * w);
}

// ---------------- lin2: h1a=relu(agg1+b1); h2=h1a@W2; agg2=h2*dinv^2 -------
__global__ __launch_bounds__(256) void k_lin2(const float* __restrict__ agg1,
                                              const float* __restrict__ b1,
                                              const float* __restrict__ W2,
                                              const float* __restrict__ dinv,
                                              float* __restrict__ h2,
                                              float* __restrict__ agg2, int N) {
    __shared__ float sw[F1 * F2];  // 408
    __shared__ float sb[F1];
    int tid = threadIdx.x;
    for (int i = tid; i < F1 * F2; i += 256) sw[i] = W2[i];
    if (tid < F1) sb[tid] = b1[tid];
    __syncthreads();

    int i = blockIdx.x * 256 + tid;
    if (i >= N) return;
    float acc[F2] = {0, 0, 0, 0, 0, 0};
    const float* row = agg1 + (size_t)i * F1;
    for (int k = 0; k < F1; k += 4) {
        float4 v4 = *(const float4*)&row[k];
        float vv[4] = {v4.x, v4.y, v4.z, v4.w};
#pragma unroll
        for (int u = 0; u < 4; u++) {
            float v = vv[u] + sb[k + u];
            v = v > 0.0f ? v : 0.0f;
#pragma unroll
            for (int c = 0; c < F2; c++) acc[c] += v * sw[(k + u) * F2 + c];
        }
    }
    float d = dinv[i];
    float d2 = d * d;
#pragma unroll
    for (int c = 0; c < F2; c++) {
        h2[(size_t)i * F2 + c] = acc[c];
        agg2[(size_t)i * F2 + c] = acc[c] * d2;
    }
}

// ---------------- agg2 edge scatter: agg2[dst] += h2[src]*norm -------------
__global__ void k_agg2(const int* __restrict__ src, const int* __restrict__ dst,
                       const float* __restrict__ nrm, const float* __restrict__ h2,
                       float* __restrict__ agg2, int E) {
    int e = blockIdx.x * blockDim.x + threadIdx.x;
    if (e >= E) return;
    int s = src[e], d = dst[e];
    float w = nrm[e];
#pragma unroll
    for (int c = 0; c < F2; c++)
        atomicAdd(&agg2[(size_t)d * F2 + c], h2[(size_t)s * F2 + c] * w);
}

// ---------------- final: relu(agg2+b2) @ Wl + bl @ Wl2 + bl2 -> pool -------
__global__ void k_final(const float* __restrict__ agg2, const float* __restrict__ b2,
                        const float* __restrict__ Wl, const float* __restrict__ bl,
                        const float* __restrict__ Wl2, const float* __restrict__ bl2,
                        const int* __restrict__ batch, float* __restrict__ pool, int N) {
    int i = blockIdx.x * blockDim.x + threadIdx.x;
    if (i >= N) return;
    float h[F2];
#pragma unroll
    for (int c = 0; c < F2; c++) {
        float v = agg2[(size_t)i * F2 + c] + b2[c];
        h[c] = v > 0.0f ? v : 0.0f;
    }
    float y = bl2[0];
#pragma unroll
    for (int j = 0; j < 3; j++) {
        float a = bl[j];
#pragma unroll
        for (int c = 0; c < F2; c++) a += h[c] * Wl[c * 3 + j];
        y += a * Wl2[j];
    }
    atomicAdd(&pool[batch[i]], y);
}

// ---------------- sigmoid ----------------
__global__ void k_sig(const float* __restrict__ pool, float* __restrict__ out, int G) {
    int g = blockIdx.x * blockDim.x + threadIdx.x;
    if (g < G) out[g] = 1.0f / (1.0f + expf(-pool[g]));
}

extern "C" void kernel_launch(void* const* d_in, const int* in_sizes, int n_in,
                              void* d_out, int out_size, void* d_ws, size_t ws_size,
                              hipStream_t stream) {
    const float* x     = (const float*)d_in[0];
    const int*   ei    = (const int*)d_in[1];
    const int*   batch = (const int*)d_in[2];
    const float* W1    = (const float*)d_in[3];
    const float* b1    = (const float*)d_in[4];
    const float* W2    = (const float*)d_in[5];
    const float* b2    = (const float*)d_in[6];
    const float* Wl    = (const float*)d_in[7];
    const float* bl    = (const float*)d_in[8];
    const float* Wl2   = (const float*)d_in[9];
    const float* bl2   = (const float*)d_in[10];
    float* out = (float*)d_out;

    int N = in_sizes[0] / F0;   // 50000
    int E = in_sizes[1] / 2;    // 512000
    int G = out_size;           // 512
    const int* src = ei;
    const int* dst = ei + E;

    float* ws = (float*)d_ws;
    size_t off = 0;
    auto alloc = [&](size_t n) { float* p = ws + off; off += (n + 255) & ~(size_t)255; return p; };
    float* deg  = alloc(N);              // becomes dinv after k_rsqrt
    float* nrm  = alloc(E);
    float* h1   = alloc((size_t)N * F1);
    float* agg1 = alloc((size_t)N * F1);
    float* h2   = alloc((size_t)N * F2);
    float* agg2 = alloc((size_t)N * F2);
    float* pool = alloc(G);

    const int B = 256;
    int mx = N > G ? N : G;
    k_init<<<(mx + B - 1) / B, B, 0, stream>>>(deg, pool, N, G);
    k_degcount<<<(E + B - 1) / B, B, 0, stream>>>(dst, deg, E);
    k_rsqrt<<<(N + B - 1) / B, B, 0, stream>>>(deg, N);
    k_norm<<<(E + B - 1) / B, B, 0, stream>>>(src, dst, deg, nrm, E);
    k_lin1<<<(N + 63) / 64, 256, 0, stream>>>(x, W1, deg, h1, agg1, N);
    k_agg1<<<(E + 3) / 4, 256, 0, stream>>>(src, dst, nrm, h1, agg1, E);
    k_lin2<<<(N + 255) / 256, 256, 0, stream>>>(agg1, b1, W2, deg, h2, agg2, N);
    k_agg2<<<(E + 255) / 256, 256, 0, stream>>>(src, dst, nrm, h2, agg2, E);
    k_final<<<(N + 255) / 256, 256, 0, stream>>>(agg2, b2, Wl, bl, Wl2, bl2, batch, pool, N);
    k_sig<<<(G + 255) / 256, 256, 0, stream>>>(pool, out, G);
}

// Round 2
// 235.943 us; speedup vs baseline: 1.9194x; 1.9194x over previous
//
#include <hip/hip_runtime.h>
#include <math.h>

#define F0 136
#define F1 68
#define F2 6

// ================= init: counts=0 (int), pool=0 =================
__global__ void k_init(int* __restrict__ counts, float* __restrict__ pool, int N, int G) {
    int i = blockIdx.x * blockDim.x + threadIdx.x;
    if (i < N) counts[i] = 0;
    if (i < G) pool[i] = 0.0f;
}

// ================= in-degree histogram over dst =================
__global__ void k_hist(const int* __restrict__ dst, int* __restrict__ counts, int E) {
    int e = blockIdx.x * blockDim.x + threadIdx.x;
    if (e < E) atomicAdd(&counts[dst[e]], 1);
}

// ================= dinv = rsqrt(counts + 1)  (self loop) =================
__global__ void k_dinv(const int* __restrict__ counts, float* __restrict__ dinv, int N) {
    int i = blockIdx.x * blockDim.x + threadIdx.x;
    if (i < N) dinv[i] = rsqrtf((float)counts[i] + 1.0f);
}

// ================= scan stage A: per-1024-chunk exclusive prefix ===========
// block=256 threads, each thread 4 contiguous elements
__global__ __launch_bounds__(256) void k_scanA(const int* __restrict__ counts,
                                               int* __restrict__ pre,
                                               int* __restrict__ blockSums, int N) {
    __shared__ int s[256];
    int t = threadIdx.x;
    int base = blockIdx.x * 1024 + t * 4;
    int v[4], sum = 0;
#pragma unroll
    for (int u = 0; u < 4; u++) {
        int idx = base + u;
        v[u] = (idx < N) ? counts[idx] : 0;
        sum += v[u];
    }
    s[t] = sum;
    __syncthreads();
    // inclusive Hillis-Steele scan over 256 thread sums
    for (int off = 1; off < 256; off <<= 1) {
        int y = (t >= off) ? s[t - off] : 0;
        __syncthreads();
        s[t] += y;
        __syncthreads();
    }
    int threadExcl = s[t] - sum;  // exclusive prefix for this thread's chunk
    int run = 0;
#pragma unroll
    for (int u = 0; u < 4; u++) {
        int idx = base + u;
        if (idx < N) pre[idx] = threadExcl + run;
        run += v[u];
    }
    if (t == 255) blockSums[blockIdx.x] = s[255];
}

// ================= scan stage B: exclusive scan of block sums (M<=64) ======
__global__ void k_scanB(int* __restrict__ blockSums, int M) {
    __shared__ int s[64];
    int t = threadIdx.x;
    int own = (t < M) ? blockSums[t] : 0;
    s[t] = own;
    __syncthreads();
    for (int off = 1; off < 64; off <<= 1) {
        int y = (t >= off) ? s[t - off] : 0;
        __syncthreads();
        s[t] += y;
        __syncthreads();
    }
    if (t < M) blockSums[t] = s[t] - own;  // exclusive
}

// ================= scan stage C: add block offsets; emit cursor ============
__global__ void k_scanC(int* __restrict__ row_start, int* __restrict__ cursor,
                        const int* __restrict__ blockSums, int N, int E) {
    int idx = blockIdx.x * blockDim.x + threadIdx.x;
    if (idx < N) {
        int v = row_start[idx] + blockSums[idx >> 10];
        row_start[idx] = v;
        cursor[idx] = v;
    }
    if (idx == 0) row_start[N] = E;
}

// ================= scatter edges into CSR (by dst) =========================
__global__ void k_scatter(const int* __restrict__ src, const int* __restrict__ dst,
                          const float* __restrict__ dinv, int* __restrict__ cursor,
                          int* __restrict__ ssrc, float* __restrict__ snrm, int E) {
    int e = blockIdx.x * blockDim.x + threadIdx.x;
    if (e >= E) return;
    int s = src[e], d = dst[e];
    int pos = atomicAdd(&cursor[d], 1);
    ssrc[pos] = s;
    snrm[pos] = dinv[s] * dinv[d];
}

// ================= lin1: h1 = x @ W1 =======================================
// 256 threads, 64 nodes/block, 4 threads/node (17 cols each); W1 in LDS col-major
__global__ __launch_bounds__(256) void k_lin1(const float* __restrict__ x,
                                              const float* __restrict__ W1,
                                              float* __restrict__ h1, int N) {
    __shared__ float sw[F1 * F0];  // col-major [c][k], 37 KB
    int tid = threadIdx.x;
    for (int i = tid; i < F0 * F1; i += 256) {
        int k = i / F1, c = i - k * F1;
        sw[c * F0 + k] = W1[i];
    }
    __syncthreads();

    int local = tid >> 2;
    int cq    = tid & 3;
    int c0    = cq * 17;
    int node  = blockIdx.x * 64 + local;
    if (node >= N) return;

    float acc[17];
#pragma unroll
    for (int j = 0; j < 17; j++) acc[j] = 0.0f;

    const float* xrow = x + (size_t)node * F0;
    for (int k = 0; k < F0; k += 4) {
        float4 xv = *(const float4*)&xrow[k];
#pragma unroll
        for (int j = 0; j < 17; j++) {
            float4 wv = *(const float4*)&sw[(c0 + j) * F0 + k];
            acc[j] += xv.x * wv.x + xv.y * wv.y + xv.z * wv.z + xv.w * wv.w;
        }
    }
    float* hrow = h1 + (size_t)node * F1 + c0;
#pragma unroll
    for (int j = 0; j < 17; j++) hrow[j] = acc[j];
}

// ================= fused: agg1 gather + bias + relu + (@W2) -> h2 ==========
// one wave per node; lane l covers col l (and 64+l for l<4)
__global__ __launch_bounds__(256) void k_gather1_lin2(const float* __restrict__ h1,
                                                      const float* __restrict__ dinv,
                                                      const int* __restrict__ row_start,
                                                      const int* __restrict__ ssrc,
                                                      const float* __restrict__ snrm,
                                                      const float* __restrict__ b1,
                                                      const float* __restrict__ W2,
                                                      float* __restrict__ h2, int N) {
    __shared__ float sw2[F1 * F2];  // 408 floats, row-major [k][c]
    __shared__ float sb1[F1];
    int tid = threadIdx.x;
    for (int i = tid; i < F1 * F2; i += 256) sw2[i] = W2[i];
    if (tid < F1) sb1[tid] = b1[tid];
    __syncthreads();

    int lane = tid & 63;
    int n = blockIdx.x * 4 + (tid >> 6);
    if (n >= N) return;

    bool hi = lane < (F1 - 64);      // lanes 0..3 also handle col 64+lane
    int colhi = 64 + (lane & 3);     // safe index even for inactive lanes

    float d = dinv[n];
    float d2 = d * d;
    const float* selfrow = h1 + (size_t)n * F1;
    float acc0 = selfrow[lane] * d2;
    float acc1 = hi ? selfrow[colhi] * d2 : 0.0f;

    int js = row_start[n], je = row_start[n + 1];
    for (int j = js; j < je; j++) {
        int s = ssrc[j];
        float w = snrm[j];
        const float* r = h1 + (size_t)s * F1;
        acc0 += r[lane] * w;
        if (hi) acc1 += r[colhi] * w;
    }

    float v0 = acc0 + sb1[lane];            v0 = v0 > 0.0f ? v0 : 0.0f;
    float v1 = hi ? (acc1 + sb1[colhi]) : 0.0f; v1 = v1 > 0.0f ? v1 : 0.0f;

    float p[F2];
#pragma unroll
    for (int c = 0; c < F2; c++)
        p[c] = v0 * sw2[lane * F2 + c] + v1 * sw2[colhi * F2 + c];

#pragma unroll
    for (int off = 1; off < 64; off <<= 1) {
#pragma unroll
        for (int c = 0; c < F2; c++) p[c] += __shfl_xor(p[c], off, 64);
    }
    if (lane < F2) h2[(size_t)n * F2 + lane] = p[lane];
}

// ================= fused: agg2 gather + bias + relu + head + pool ==========
// 8 lanes per node (6 active); y = relu(agg2+b2) . (Wl@Wl2) + const -> pool
__global__ __launch_bounds__(256) void k_gather2_final(const float* __restrict__ h2,
                                                       const float* __restrict__ dinv,
                                                       const int* __restrict__ row_start,
                                                       const int* __restrict__ ssrc,
                                                       const float* __restrict__ snrm,
                                                       const float* __restrict__ b2,
                                                       const float* __restrict__ Wl,
                                                       const float* __restrict__ bl,
                                                       const float* __restrict__ Wl2,
                                                       const float* __restrict__ bl2,
                                                       const int* __restrict__ batch,
                                                       float* __restrict__ pool, int N) {
    int t = blockIdx.x * blockDim.x + threadIdx.x;
    int n = t >> 3;
    int c = t & 7;
    if (n >= N) return;
    bool act = c < F2;

    float d = dinv[n];
    float acc = act ? h2[(size_t)n * F2 + c] * d * d : 0.0f;
    int js = row_start[n], je = row_start[n + 1];
    for (int j = js; j < je; j++) {
        int s = ssrc[j];
        float w = snrm[j];
        if (act) acc += h2[(size_t)s * F2 + c] * w;
    }
    float y = 0.0f;
    if (act) {
        float v = acc + b2[c];
        v = v > 0.0f ? v : 0.0f;
        float we = Wl[c * 3 + 0] * Wl2[0] + Wl[c * 3 + 1] * Wl2[1] + Wl[c * 3 + 2] * Wl2[2];
        y = v * we;
    }
    y += __shfl_xor(y, 1, 8);
    y += __shfl_xor(y, 2, 8);
    y += __shfl_xor(y, 4, 8);
    if (c == 0) {
        float cnst = bl[0] * Wl2[0] + bl[1] * Wl2[1] + bl[2] * Wl2[2] + bl2[0];
        atomicAdd(&pool[batch[n]], y + cnst);
    }
}

// ================= sigmoid =================
__global__ void k_sig(const float* __restrict__ pool, float* __restrict__ out, int G) {
    int g = blockIdx.x * blockDim.x + threadIdx.x;
    if (g < G) out[g] = 1.0f / (1.0f + expf(-pool[g]));
}

extern "C" void kernel_launch(void* const* d_in, const int* in_sizes, int n_in,
                              void* d_out, int out_size, void* d_ws, size_t ws_size,
                              hipStream_t stream) {
    const float* x     = (const float*)d_in[0];
    const int*   ei    = (const int*)d_in[1];
    const int*   batch = (const int*)d_in[2];
    const float* W1    = (const float*)d_in[3];
    const float* b1    = (const float*)d_in[4];
    const float* W2    = (const float*)d_in[5];
    const float* b2    = (const float*)d_in[6];
    const float* Wl    = (const float*)d_in[7];
    const float* bl    = (const float*)d_in[8];
    const float* Wl2   = (const float*)d_in[9];
    const float* bl2   = (const float*)d_in[10];
    float* out = (float*)d_out;

    int N = in_sizes[0] / F0;   // 50000
    int E = in_sizes[1] / 2;    // 512000
    int G = out_size;           // 512
    const int* src = ei;
    const int* dst = ei + E;

    char* ws = (char*)d_ws;
    size_t off = 0;
    auto alloc = [&](size_t bytes) {
        void* p = ws + off;
        off = (off + bytes + 255) & ~(size_t)255;
        return p;
    };
    int*   counts    = (int*)alloc((size_t)N * 4);        // reused as cursor
    int*   row_start = (int*)alloc((size_t)(N + 1) * 4);
    float* dinv      = (float*)alloc((size_t)N * 4);
    int*   ssrc      = (int*)alloc((size_t)E * 4);
    float* snrm      = (float*)alloc((size_t)E * 4);
    float* h1        = (float*)alloc((size_t)N * F1 * 4);
    float* h2        = (float*)alloc((size_t)N * F2 * 4);
    float* pool      = (float*)alloc((size_t)G * 4);
    int*   blockSums = (int*)alloc(64 * 4);

    const int B = 256;
    int nScanBlocks = (N + 1023) / 1024;   // 49

    int mx = N > G ? N : G;
    k_init<<<(mx + B - 1) / B, B, 0, stream>>>(counts, pool, N, G);
    k_hist<<<(E + B - 1) / B, B, 0, stream>>>(dst, counts, E);
    k_dinv<<<(N + B - 1) / B, B, 0, stream>>>(counts, dinv, N);
    k_scanA<<<nScanBlocks, 256, 0, stream>>>(counts, row_start, blockSums, N);
    k_scanB<<<1, 64, 0, stream>>>(blockSums, nScanBlocks);
    k_scanC<<<(N + B - 1) / B, B, 0, stream>>>(row_start, counts /*cursor*/, blockSums, N, E);
    k_scatter<<<(E + B - 1) / B, B, 0, stream>>>(src, dst, dinv, counts /*cursor*/, ssrc, snrm, E);
    k_lin1<<<(N + 63) / 64, 256, 0, stream>>>(x, W1, h1, N);
    k_gather1_lin2<<<(N + 3) / 4, 256, 0, stream>>>(h1, dinv, row_start, ssrc, snrm, b1, W2, h2, N);
    k_gather2_final<<<((N * 8) + B - 1) / B, B, 0, stream>>>(h2, dinv, row_start, ssrc, snrm,
                                                             b2, Wl, bl, Wl2, bl2, batch, pool, N);
    k_sig<<<(G + 255) / 256, 256, 0, stream>>>(pool, out, G);
}

// Round 3
// 229.168 us; speedup vs baseline: 1.9761x; 1.0296x over previous
//
#include <hip/hip_runtime.h>
#include <math.h>

#define F0 136
#define F1 68
#define F2 6

__device__ inline int rfl(int v) { return __builtin_amdgcn_readfirstlane(v); }

// ================= init: counts=0 (int), pool=0 =================
__global__ void k_init(int* __restrict__ counts, float* __restrict__ pool, int N, int G) {
    int i = blockIdx.x * blockDim.x + threadIdx.x;
    if (i < N) counts[i] = 0;
    if (i < G) pool[i] = 0.0f;
}

// ================= in-degree histogram over dst =================
__global__ void k_hist(const int* __restrict__ dst, int* __restrict__ counts, int E) {
    int e = blockIdx.x * blockDim.x + threadIdx.x;
    if (e < E) atomicAdd(&counts[dst[e]], 1);
}

// ================= transpose W1 to col-major [c][k] =================
__global__ void k_wt(const float* __restrict__ W1, float* __restrict__ Wt) {
    int i = blockIdx.x * blockDim.x + threadIdx.x;
    if (i < F0 * F1) {
        int k = i / F1, c = i - k * F1;
        Wt[c * F0 + k] = W1[i];
    }
}

// ================= scan stage A: per-1024-chunk prefix + dinv ===========
__global__ __launch_bounds__(256) void k_scanA(const int* __restrict__ counts,
                                               int* __restrict__ pre,
                                               int* __restrict__ blockSums,
                                               float* __restrict__ dinv, int N) {
    __shared__ int s[256];
    int t = threadIdx.x;
    int base = blockIdx.x * 1024 + t * 4;
    int v[4], sum = 0;
#pragma unroll
    for (int u = 0; u < 4; u++) {
        int idx = base + u;
        v[u] = (idx < N) ? counts[idx] : 0;
        if (idx < N) dinv[idx] = rsqrtf((float)v[u] + 1.0f);  // self loop
        sum += v[u];
    }
    s[t] = sum;
    __syncthreads();
    for (int off = 1; off < 256; off <<= 1) {
        int y = (t >= off) ? s[t - off] : 0;
        __syncthreads();
        s[t] += y;
        __syncthreads();
    }
    int threadExcl = s[t] - sum;
    int run = 0;
#pragma unroll
    for (int u = 0; u < 4; u++) {
        int idx = base + u;
        if (idx < N) pre[idx] = threadExcl + run;
        run += v[u];
    }
    if (t == 255) blockSums[blockIdx.x] = s[255];
}

// ================= scan stage B: exclusive scan of block sums (M<=64) ======
__global__ void k_scanB(int* __restrict__ blockSums, int M) {
    __shared__ int s[64];
    int t = threadIdx.x;
    int own = (t < M) ? blockSums[t] : 0;
    s[t] = own;
    __syncthreads();
    for (int off = 1; off < 64; off <<= 1) {
        int y = (t >= off) ? s[t - off] : 0;
        __syncthreads();
        s[t] += y;
        __syncthreads();
    }
    if (t < M) blockSums[t] = s[t] - own;
}

// ================= scan stage C: add block offsets; emit cursor ============
__global__ void k_scanC(int* __restrict__ row_start, int* __restrict__ cursor,
                        const int* __restrict__ blockSums, int N, int E) {
    int idx = blockIdx.x * blockDim.x + threadIdx.x;
    if (idx < N) {
        int v = row_start[idx] + blockSums[idx >> 10];
        row_start[idx] = v;
        cursor[idx] = v;
    }
    if (idx == 0) row_start[N] = E;
}

// ================= scatter edges into CSR (by dst) =========================
__global__ void k_scatter(const int* __restrict__ src, const int* __restrict__ dst,
                          const float* __restrict__ dinv, int* __restrict__ cursor,
                          int* __restrict__ ssrc, float* __restrict__ snrm, int E) {
    int e = blockIdx.x * blockDim.x + threadIdx.x;
    if (e >= E) return;
    int s = src[e], d = dst[e];
    int pos = atomicAdd(&cursor[d], 1);
    ssrc[pos] = s;
    snrm[pos] = dinv[s] * dinv[d];
}

// ================= lin1: h1 = x @ W1, no LDS ===============================
// one wave = 64 nodes x 17 cols; W (col-major) read wave-uniform -> s_load.
__global__ __launch_bounds__(256) void k_lin1(const float* __restrict__ x,
                                              const float* __restrict__ Wt,
                                              float* __restrict__ h1, int N) {
    int lane = threadIdx.x & 63;
    int cq   = threadIdx.x >> 6;          // wave id in block: 0..3
    int c0   = cq * 17;
    int node = blockIdx.x * 64 + lane;
    if (node >= N) return;

    int rb[17];
#pragma unroll
    for (int j = 0; j < 17; j++) rb[j] = rfl((c0 + j) * F0);

    float acc[17];
#pragma unroll
    for (int j = 0; j < 17; j++) acc[j] = 0.0f;

    const float* xrow = x + (size_t)node * F0;
    for (int k = 0; k < F0; k += 4) {
        float4 xv = *(const float4*)&xrow[k];
#pragma unroll
        for (int j = 0; j < 17; j++) {
            float4 wv = *(const float4*)&Wt[rb[j] + k];
            acc[j] += xv.x * wv.x + xv.y * wv.y + xv.z * wv.z + xv.w * wv.w;
        }
    }
    float* hrow = h1 + (size_t)node * F1 + c0;
#pragma unroll
    for (int j = 0; j < 17; j++) hrow[j] = acc[j];
}

// ================= fused: agg1 gather + bias + relu + (@W2) -> h2 ==========
// one wave per node; lane l covers col l (lanes 0..3 also col 64+l); unroll x4
__global__ __launch_bounds__(256) void k_gather1_lin2(const float* __restrict__ h1,
                                                      const float* __restrict__ dinv,
                                                      const int* __restrict__ row_start,
                                                      const int* __restrict__ ssrc,
                                                      const float* __restrict__ snrm,
                                                      const float* __restrict__ b1,
                                                      const float* __restrict__ W2,
                                                      float* __restrict__ h2, int N) {
    __shared__ float sw2[F1 * F2];
    __shared__ float sb1[F1];
    int tid = threadIdx.x;
    for (int i = tid; i < F1 * F2; i += 256) sw2[i] = W2[i];
    if (tid < F1) sb1[tid] = b1[tid];
    __syncthreads();

    int lane = tid & 63;
    int n = blockIdx.x * 4 + (tid >> 6);
    if (n >= N) return;

    bool hi = lane < (F1 - 64);
    int colhi = 64 + (lane & 3);

    float d = dinv[n];
    float d2 = d * d;
    const float* selfrow = h1 + (size_t)n * F1;
    float acc0 = selfrow[lane] * d2;
    float acc1 = hi ? selfrow[colhi] * d2 : 0.0f;

    int js = row_start[n], je = row_start[n + 1];
    int j = js;
    for (; j + 3 < je; j += 4) {
        int s0 = rfl(ssrc[j + 0]), s1 = rfl(ssrc[j + 1]);
        int s2 = rfl(ssrc[j + 2]), s3 = rfl(ssrc[j + 3]);
        float w0 = snrm[j + 0], w1 = snrm[j + 1], w2 = snrm[j + 2], w3 = snrm[j + 3];
        const float* r0 = h1 + (size_t)s0 * F1;
        const float* r1 = h1 + (size_t)s1 * F1;
        const float* r2 = h1 + (size_t)s2 * F1;
        const float* r3 = h1 + (size_t)s3 * F1;
        float a0 = r0[lane], a1 = r1[lane], a2 = r2[lane], a3 = r3[lane];
        acc0 = fmaf(a0, w0, acc0);
        acc0 = fmaf(a1, w1, acc0);
        acc0 = fmaf(a2, w2, acc0);
        acc0 = fmaf(a3, w3, acc0);
        if (hi) {
            float b0v = r0[colhi], b1v = r1[colhi], b2v = r2[colhi], b3v = r3[colhi];
            acc1 = fmaf(b0v, w0, acc1);
            acc1 = fmaf(b1v, w1, acc1);
            acc1 = fmaf(b2v, w2, acc1);
            acc1 = fmaf(b3v, w3, acc1);
        }
    }
    for (; j < je; j++) {
        int s = rfl(ssrc[j]);
        float w = snrm[j];
        const float* r = h1 + (size_t)s * F1;
        acc0 = fmaf(r[lane], w, acc0);
        if (hi) acc1 = fmaf(r[colhi], w, acc1);
    }

    float v0 = acc0 + sb1[lane];                 v0 = v0 > 0.0f ? v0 : 0.0f;
    float v1 = hi ? (acc1 + sb1[colhi]) : 0.0f;  v1 = v1 > 0.0f ? v1 : 0.0f;

    float p[F2];
#pragma unroll
    for (int c = 0; c < F2; c++)
        p[c] = v0 * sw2[lane * F2 + c] + v1 * sw2[colhi * F2 + c];

#pragma unroll
    for (int off = 1; off < 64; off <<= 1) {
#pragma unroll
        for (int c = 0; c < F2; c++) p[c] += __shfl_xor(p[c], off, 64);
    }
    if (lane < F2) h2[(size_t)n * F2 + lane] = p[lane];
}

// ================= fused: agg2 gather + bias + relu + head + pool ==========
// 8 lanes per node (6 active); unroll x4
__global__ __launch_bounds__(256) void k_gather2_final(const float* __restrict__ h2,
                                                       const float* __restrict__ dinv,
                                                       const int* __restrict__ row_start,
                                                       const int* __restrict__ ssrc,
                                                       const float* __restrict__ snrm,
                                                       const float* __restrict__ b2,
                                                       const float* __restrict__ Wl,
                                                       const float* __restrict__ bl,
                                                       const float* __restrict__ Wl2,
                                                       const float* __restrict__ bl2,
                                                       const int* __restrict__ batch,
                                                       float* __restrict__ pool, int N) {
    int t = blockIdx.x * blockDim.x + threadIdx.x;
    int n = t >> 3;
    int c = t & 7;
    if (n >= N) return;
    bool act = c < F2;
    int cc = act ? c : 0;

    float d = dinv[n];
    float acc = h2[(size_t)n * F2 + cc] * d * d;
    int js = row_start[n], je = row_start[n + 1];
    int j = js;
    for (; j + 3 < je; j += 4) {
        int s0 = ssrc[j + 0], s1 = ssrc[j + 1], s2 = ssrc[j + 2], s3 = ssrc[j + 3];
        float w0 = snrm[j + 0], w1 = snrm[j + 1], w2 = snrm[j + 2], w3 = snrm[j + 3];
        float a0 = h2[(size_t)s0 * F2 + cc];
        float a1 = h2[(size_t)s1 * F2 + cc];
        float a2 = h2[(size_t)s2 * F2 + cc];
        float a3 = h2[(size_t)s3 * F2 + cc];
        acc = fmaf(a0, w0, acc);
        acc = fmaf(a1, w1, acc);
        acc = fmaf(a2, w2, acc);
        acc = fmaf(a3, w3, acc);
    }
    for (; j < je; j++) acc = fmaf(h2[(size_t)ssrc[j] * F2 + cc], snrm[j], acc);

    float y = 0.0f;
    if (act) {
        float v = acc + b2[c];
        v = v > 0.0f ? v : 0.0f;
        float we = Wl[c * 3 + 0] * Wl2[0] + Wl[c * 3 + 1] * Wl2[1] + Wl[c * 3 + 2] * Wl2[2];
        y = v * we;
    }
    y += __shfl_xor(y, 1, 8);
    y += __shfl_xor(y, 2, 8);
    y += __shfl_xor(y, 4, 8);
    if (c == 0) {
        float cnst = bl[0] * Wl2[0] + bl[1] * Wl2[1] + bl[2] * Wl2[2] + bl2[0];
        atomicAdd(&pool[batch[n]], y + cnst);
    }
}

// ================= sigmoid =================
__global__ void k_sig(const float* __restrict__ pool, float* __restrict__ out, int G) {
    int g = blockIdx.x * blockDim.x + threadIdx.x;
    if (g < G) out[g] = 1.0f / (1.0f + expf(-pool[g]));
}

extern "C" void kernel_launch(void* const* d_in, const int* in_sizes, int n_in,
                              void* d_out, int out_size, void* d_ws, size_t ws_size,
                              hipStream_t stream) {
    const float* x     = (const float*)d_in[0];
    const int*   ei    = (const int*)d_in[1];
    const int*   batch = (const int*)d_in[2];
    const float* W1    = (const float*)d_in[3];
    const float* b1    = (const float*)d_in[4];
    const float* W2    = (const float*)d_in[5];
    const float* b2    = (const float*)d_in[6];
    const float* Wl    = (const float*)d_in[7];
    const float* bl    = (const float*)d_in[8];
    const float* Wl2   = (const float*)d_in[9];
    const float* bl2   = (const float*)d_in[10];
    float* out = (float*)d_out;

    int N = in_sizes[0] / F0;   // 50000
    int E = in_sizes[1] / 2;    // 512000
    int G = out_size;           // 512
    const int* src = ei;
    const int* dst = ei + E;

    char* ws = (char*)d_ws;
    size_t off = 0;
    auto alloc = [&](size_t bytes) {
        void* p = ws + off;
        off = (off + bytes + 255) & ~(size_t)255;
        return p;
    };
    int*   counts    = (int*)alloc((size_t)N * 4);        // reused as cursor
    int*   row_start = (int*)alloc((size_t)(N + 1) * 4);
    float* dinv      = (float*)alloc((size_t)N * 4);
    int*   ssrc      = (int*)alloc((size_t)E * 4);
    float* snrm      = (float*)alloc((size_t)E * 4);
    float* h1        = (float*)alloc((size_t)N * F1 * 4);
    float* h2        = (float*)alloc((size_t)N * F2 * 4);
    float* pool      = (float*)alloc((size_t)G * 4);
    int*   blockSums = (int*)alloc(64 * 4);
    float* Wt        = (float*)alloc((size_t)F0 * F1 * 4);

    const int B = 256;
    int nScanBlocks = (N + 1023) / 1024;   // 49

    int mx = N > G ? N : G;
    k_init<<<(mx + B - 1) / B, B, 0, stream>>>(counts, pool, N, G);
    k_hist<<<(E + B - 1) / B, B, 0, stream>>>(dst, counts, E);
    k_wt<<<(F0 * F1 + B - 1) / B, B, 0, stream>>>(W1, Wt);
    k_scanA<<<nScanBlocks, 256, 0, stream>>>(counts, row_start, blockSums, dinv, N);
    k_scanB<<<1, 64, 0, stream>>>(blockSums, nScanBlocks);
    k_scanC<<<(N + B - 1) / B, B, 0, stream>>>(row_start, counts /*cursor*/, blockSums, N, E);
    k_scatter<<<(E + B - 1) / B, B, 0, stream>>>(src, dst, dinv, counts /*cursor*/, ssrc, snrm, E);
    k_lin1<<<(N + 63) / 64, 256, 0, stream>>>(x, Wt, h1, N);
    k_gather1_lin2<<<(N + 3) / 4, 256, 0, stream>>>(h1, dinv, row_start, ssrc, snrm, b1, W2, h2, N);
    k_gather2_final<<<((N * 8) + B - 1) / B, B, 0, stream>>>(h2, dinv, row_start, ssrc, snrm,
                                                             b2, Wl, bl, Wl2, bl2, batch, pool, N);
    k_sig<<<(G + 255) / 256, 256, 0, stream>>>(pool, out, G);
}

// Round 4
// 226.445 us; speedup vs baseline: 1.9999x; 1.0120x over previous
//
#include <hip/hip_runtime.h>
#include <math.h>

#define F0 136
#define F1 68
#define F2 6

__device__ inline int rfl(int v) { return __builtin_amdgcn_readfirstlane(v); }

__device__ inline float bf2f(unsigned short u) {
    union { unsigned int i; float f; } v; v.i = ((unsigned int)u) << 16; return v.f;
}
__device__ inline unsigned short f2bf(float f) {
    union { float f; unsigned int i; } v; v.f = f;
    unsigned int r = v.i + 0x7FFFu + ((v.i >> 16) & 1u);  // round-nearest-even
    return (unsigned short)(r >> 16);
}

// ================= init: counts=0 (int), pool=0 =================
__global__ void k_init(int* __restrict__ counts, float* __restrict__ pool, int N, int G) {
    int i = blockIdx.x * blockDim.x + threadIdx.x;
    if (i < N) counts[i] = 0;
    if (i < G) pool[i] = 0.0f;
}

// ================= in-degree histogram over dst =================
__global__ void k_hist(const int* __restrict__ dst, int* __restrict__ counts, int E) {
    int e = blockIdx.x * blockDim.x + threadIdx.x;
    if (e < E) atomicAdd(&counts[dst[e]], 1);
}

// ================= transpose W1 to col-major [c][k] =================
__global__ void k_wt(const float* __restrict__ W1, float* __restrict__ Wt) {
    int i = blockIdx.x * blockDim.x + threadIdx.x;
    if (i < F0 * F1) {
        int k = i / F1, c = i - k * F1;
        Wt[c * F0 + k] = W1[i];
    }
}

// ================= scan stage A: per-1024-chunk prefix + dinv ===========
__global__ __launch_bounds__(256) void k_scanA(const int* __restrict__ counts,
                                               int* __restrict__ pre,
                                               int* __restrict__ blockSums,
                                               float* __restrict__ dinv, int N) {
    __shared__ int s[256];
    int t = threadIdx.x;
    int base = blockIdx.x * 1024 + t * 4;
    int v[4], sum = 0;
#pragma unroll
    for (int u = 0; u < 4; u++) {
        int idx = base + u;
        v[u] = (idx < N) ? counts[idx] : 0;
        if (idx < N) dinv[idx] = rsqrtf((float)v[u] + 1.0f);  // self loop
        sum += v[u];
    }
    s[t] = sum;
    __syncthreads();
    for (int off = 1; off < 256; off <<= 1) {
        int y = (t >= off) ? s[t - off] : 0;
        __syncthreads();
        s[t] += y;
        __syncthreads();
    }
    int threadExcl = s[t] - sum;
    int run = 0;
#pragma unroll
    for (int u = 0; u < 4; u++) {
        int idx = base + u;
        if (idx < N) pre[idx] = threadExcl + run;
        run += v[u];
    }
    if (t == 255) blockSums[blockIdx.x] = s[255];
}

// ================= scan stage B: exclusive scan of block sums (M<=64) ======
__global__ void k_scanB(int* __restrict__ blockSums, int M) {
    __shared__ int s[64];
    int t = threadIdx.x;
    int own = (t < M) ? blockSums[t] : 0;
    s[t] = own;
    __syncthreads();
    for (int off = 1; off < 64; off <<= 1) {
        int y = (t >= off) ? s[t - off] : 0;
        __syncthreads();
        s[t] += y;
        __syncthreads();
    }
    if (t < M) blockSums[t] = s[t] - own;
}

// ================= scan stage C: add block offsets; emit cursor ============
__global__ void k_scanC(int* __restrict__ row_start, int* __restrict__ cursor,
                        const int* __restrict__ blockSums, int N, int E) {
    int idx = blockIdx.x * blockDim.x + threadIdx.x;
    if (idx < N) {
        int v = row_start[idx] + blockSums[idx >> 10];
        row_start[idx] = v;
        cursor[idx] = v;
    }
    if (idx == 0) row_start[N] = E;
}

// ================= scatter edges into CSR (by dst) =========================
__global__ void k_scatter(const int* __restrict__ src, const int* __restrict__ dst,
                          const float* __restrict__ dinv, int* __restrict__ cursor,
                          int* __restrict__ ssrc, float* __restrict__ snrm, int E) {
    int e = blockIdx.x * blockDim.x + threadIdx.x;
    if (e >= E) return;
    int s = src[e], d = dst[e];
    int pos = atomicAdd(&cursor[d], 1);
    ssrc[pos] = s;
    snrm[pos] = dinv[s] * dinv[d];
}

// ================= lin1: h1 = x @ W1 (bf16 out), no LDS ====================
// one wave = 64 nodes x 17 cols; W (col-major) read wave-uniform -> s_load.
__global__ __launch_bounds__(256) void k_lin1(const float* __restrict__ x,
                                              const float* __restrict__ Wt,
                                              unsigned short* __restrict__ h1b, int N) {
    int lane = threadIdx.x & 63;
    int cq   = threadIdx.x >> 6;          // wave id in block: 0..3
    int c0   = cq * 17;
    int node = blockIdx.x * 64 + lane;
    if (node >= N) return;

    int rb[17];
#pragma unroll
    for (int j = 0; j < 17; j++) rb[j] = rfl((c0 + j) * F0);

    float acc[17];
#pragma unroll
    for (int j = 0; j < 17; j++) acc[j] = 0.0f;

    const float* xrow = x + (size_t)node * F0;
    for (int k = 0; k < F0; k += 4) {
        float4 xv = *(const float4*)&xrow[k];
#pragma unroll
        for (int j = 0; j < 17; j++) {
            float4 wv = *(const float4*)&Wt[rb[j] + k];
            acc[j] += xv.x * wv.x + xv.y * wv.y + xv.z * wv.z + xv.w * wv.w;
        }
    }
    unsigned short* hrow = h1b + (size_t)node * F1 + c0;
#pragma unroll
    for (int j = 0; j < 17; j++) hrow[j] = f2bf(acc[j]);
}

// ================= fused: agg1 gather (bf16) + bias + relu + (@W2) -> h2 ===
// one wave per node; lane l covers col l (lanes 0..3 also col 64+l); unroll x4
__global__ __launch_bounds__(256) void k_gather1_lin2(const unsigned short* __restrict__ h1b,
                                                      const float* __restrict__ dinv,
                                                      const int* __restrict__ row_start,
                                                      const int* __restrict__ ssrc,
                                                      const float* __restrict__ snrm,
                                                      const float* __restrict__ b1,
                                                      const float* __restrict__ W2,
                                                      float* __restrict__ h2, int N) {
    __shared__ float sw2[F1 * F2];
    __shared__ float sb1[F1];
    int tid = threadIdx.x;
    for (int i = tid; i < F1 * F2; i += 256) sw2[i] = W2[i];
    if (tid < F1) sb1[tid] = b1[tid];
    __syncthreads();

    int lane = tid & 63;
    int n = blockIdx.x * 4 + (tid >> 6);
    if (n >= N) return;

    bool hi = lane < (F1 - 64);
    int colhi = 64 + (lane & 3);

    float d = dinv[n];
    float d2 = d * d;
    const unsigned short* selfrow = h1b + (size_t)n * F1;
    float acc0 = bf2f(selfrow[lane]) * d2;
    float acc1 = hi ? bf2f(selfrow[colhi]) * d2 : 0.0f;

    int js = row_start[n], je = row_start[n + 1];
    int j = js;
    for (; j + 3 < je; j += 4) {
        int s0 = rfl(ssrc[j + 0]), s1 = rfl(ssrc[j + 1]);
        int s2 = rfl(ssrc[j + 2]), s3 = rfl(ssrc[j + 3]);
        float w0 = snrm[j + 0], w1 = snrm[j + 1], w2 = snrm[j + 2], w3 = snrm[j + 3];
        const unsigned short* r0 = h1b + (size_t)s0 * F1;
        const unsigned short* r1 = h1b + (size_t)s1 * F1;
        const unsigned short* r2 = h1b + (size_t)s2 * F1;
        const unsigned short* r3 = h1b + (size_t)s3 * F1;
        float a0 = bf2f(r0[lane]), a1 = bf2f(r1[lane]);
        float a2 = bf2f(r2[lane]), a3 = bf2f(r3[lane]);
        acc0 = fmaf(a0, w0, acc0);
        acc0 = fmaf(a1, w1, acc0);
        acc0 = fmaf(a2, w2, acc0);
        acc0 = fmaf(a3, w3, acc0);
        if (hi) {
            float b0v = bf2f(r0[colhi]), b1v = bf2f(r1[colhi]);
            float b2v = bf2f(r2[colhi]), b3v = bf2f(r3[colhi]);
            acc1 = fmaf(b0v, w0, acc1);
            acc1 = fmaf(b1v, w1, acc1);
            acc1 = fmaf(b2v, w2, acc1);
            acc1 = fmaf(b3v, w3, acc1);
        }
    }
    for (; j < je; j++) {
        int s = rfl(ssrc[j]);
        float w = snrm[j];
        const unsigned short* r = h1b + (size_t)s * F1;
        acc0 = fmaf(bf2f(r[lane]), w, acc0);
        if (hi) acc1 = fmaf(bf2f(r[colhi]), w, acc1);
    }

    float v0 = acc0 + sb1[lane];                 v0 = v0 > 0.0f ? v0 : 0.0f;
    float v1 = hi ? (acc1 + sb1[colhi]) : 0.0f;  v1 = v1 > 0.0f ? v1 : 0.0f;

    float p[F2];
#pragma unroll
    for (int c = 0; c < F2; c++)
        p[c] = v0 * sw2[lane * F2 + c] + v1 * sw2[colhi * F2 + c];

#pragma unroll
    for (int off = 1; off < 64; off <<= 1) {
#pragma unroll
        for (int c = 0; c < F2; c++) p[c] += __shfl_xor(p[c], off, 64);
    }
    if (lane < F2) h2[(size_t)n * F2 + lane] = p[lane];
}

// ================= fused: agg2 gather + bias + relu + head + pool ==========
// 8 lanes per node; lanes parallelize over EDGES (each loads full 6-col row),
// then 3-step shfl_xor reduce within the 8-lane group.
__global__ __launch_bounds__(256) void k_gather2_final(const float* __restrict__ h2,
                                                       const float* __restrict__ dinv,
                                                       const int* __restrict__ row_start,
                                                       const int* __restrict__ ssrc,
                                                       const float* __restrict__ snrm,
                                                       const float* __restrict__ b2,
                                                       const float* __restrict__ Wl,
                                                       const float* __restrict__ bl,
                                                       const float* __restrict__ Wl2,
                                                       const float* __restrict__ bl2,
                                                       const int* __restrict__ batch,
                                                       float* __restrict__ pool, int N) {
    int t = blockIdx.x * blockDim.x + threadIdx.x;
    int n = t >> 3;
    int l = t & 7;
    if (n >= N) return;

    float acc[F2] = {0, 0, 0, 0, 0, 0};
    if (l == 0) {  // self-loop term
        float d = dinv[n];
        float d2 = d * d;
        const float* sr = h2 + (size_t)n * F2;
        float2 p0 = *(const float2*)&sr[0];
        float2 p1 = *(const float2*)&sr[2];
        float2 p2 = *(const float2*)&sr[4];
        acc[0] = p0.x * d2; acc[1] = p0.y * d2;
        acc[2] = p1.x * d2; acc[3] = p1.y * d2;
        acc[4] = p2.x * d2; acc[5] = p2.y * d2;
    }

    int js = row_start[n], je = row_start[n + 1];
    for (int j = js + l; j < je; j += 8) {
        int s = ssrc[j];
        float w = snrm[j];
        const float* r = h2 + (size_t)s * F2;
        float2 p0 = *(const float2*)&r[0];
        float2 p1 = *(const float2*)&r[2];
        float2 p2 = *(const float2*)&r[4];
        acc[0] = fmaf(p0.x, w, acc[0]);
        acc[1] = fmaf(p0.y, w, acc[1]);
        acc[2] = fmaf(p1.x, w, acc[2]);
        acc[3] = fmaf(p1.y, w, acc[3]);
        acc[4] = fmaf(p2.x, w, acc[4]);
        acc[5] = fmaf(p2.y, w, acc[5]);
    }

#pragma unroll
    for (int off = 1; off < 8; off <<= 1) {
#pragma unroll
        for (int c = 0; c < F2; c++) acc[c] += __shfl_xor(acc[c], off, 8);
    }

    if (l == 0) {
        float y = 0.0f;
#pragma unroll
        for (int c = 0; c < F2; c++) {
            float v = acc[c] + b2[c];
            v = v > 0.0f ? v : 0.0f;
            float we = Wl[c * 3 + 0] * Wl2[0] + Wl[c * 3 + 1] * Wl2[1] + Wl[c * 3 + 2] * Wl2[2];
            y = fmaf(v, we, y);
        }
        float cnst = bl[0] * Wl2[0] + bl[1] * Wl2[1] + bl[2] * Wl2[2] + bl2[0];
        atomicAdd(&pool[batch[n]], y + cnst);
    }
}

// ================= sigmoid =================
__global__ void k_sig(const float* __restrict__ pool, float* __restrict__ out, int G) {
    int g = blockIdx.x * blockDim.x + threadIdx.x;
    if (g < G) out[g] = 1.0f / (1.0f + expf(-pool[g]));
}

extern "C" void kernel_launch(void* const* d_in, const int* in_sizes, int n_in,
                              void* d_out, int out_size, void* d_ws, size_t ws_size,
                              hipStream_t stream) {
    const float* x     = (const float*)d_in[0];
    const int*   ei    = (const int*)d_in[1];
    const int*   batch = (const int*)d_in[2];
    const float* W1    = (const float*)d_in[3];
    const float* b1    = (const float*)d_in[4];
    const float* W2    = (const float*)d_in[5];
    const float* b2    = (const float*)d_in[6];
    const float* Wl    = (const float*)d_in[7];
    const float* bl    = (const float*)d_in[8];
    const float* Wl2   = (const float*)d_in[9];
    const float* bl2   = (const float*)d_in[10];
    float* out = (float*)d_out;

    int N = in_sizes[0] / F0;   // 50000
    int E = in_sizes[1] / 2;    // 512000
    int G = out_size;           // 512
    const int* src = ei;
    const int* dst = ei + E;

    char* ws = (char*)d_ws;
    size_t off = 0;
    auto alloc = [&](size_t bytes) {
        void* p = ws + off;
        off = (off + bytes + 255) & ~(size_t)255;
        return p;
    };
    int*   counts    = (int*)alloc((size_t)N * 4);        // reused as cursor
    int*   row_start = (int*)alloc((size_t)(N + 1) * 4);
    float* dinv      = (float*)alloc((size_t)N * 4);
    int*   ssrc      = (int*)alloc((size_t)E * 4);
    float* snrm      = (float*)alloc((size_t)E * 4);
    unsigned short* h1b = (unsigned short*)alloc((size_t)N * F1 * 2);
    float* h2        = (float*)alloc((size_t)N * F2 * 4);
    float* pool      = (float*)alloc((size_t)G * 4);
    int*   blockSums = (int*)alloc(64 * 4);
    float* Wt        = (float*)alloc((size_t)F0 * F1 * 4);

    const int B = 256;
    int nScanBlocks = (N + 1023) / 1024;   // 49

    int mx = N > G ? N : G;
    k_init<<<(mx + B - 1) / B, B, 0, stream>>>(counts, pool, N, G);
    k_hist<<<(E + B - 1) / B, B, 0, stream>>>(dst, counts, E);
    k_wt<<<(F0 * F1 + B - 1) / B, B, 0, stream>>>(W1, Wt);
    k_scanA<<<nScanBlocks, 256, 0, stream>>>(counts, row_start, blockSums, dinv, N);
    k_scanB<<<1, 64, 0, stream>>>(blockSums, nScanBlocks);
    k_scanC<<<(N + B - 1) / B, B, 0, stream>>>(row_start, counts /*cursor*/, blockSums, N, E);
    k_scatter<<<(E + B - 1) / B, B, 0, stream>>>(src, dst, dinv, counts /*cursor*/, ssrc, snrm, E);
    k_lin1<<<(N + 63) / 64, 256, 0, stream>>>(x, Wt, h1b, N);
    k_gather1_lin2<<<(N + 3) / 4, 256, 0, stream>>>(h1b, dinv, row_start, ssrc, snrm, b1, W2, h2, N);
    k_gather2_final<<<((N * 8) + B - 1) / B, B, 0, stream>>>(h2, dinv, row_start, ssrc, snrm,
                                                             b2, Wl, bl, Wl2, bl2, batch, pool, N);
    k_sig<<<(G + 255) / 256, 256, 0, stream>>>(pool, out, G);
}

// Round 5
// 173.305 us; speedup vs baseline: 2.6131x; 1.3066x over previous
//
#include <hip/hip_runtime.h>
#include <math.h>

#define F0 136
#define F1 68
#define F2 6

__device__ inline int rfl(int v) { return __builtin_amdgcn_readfirstlane(v); }

__device__ inline float bf2f(unsigned short u) {
    union { unsigned int i; float f; } v; v.i = ((unsigned int)u) << 16; return v.f;
}
__device__ inline unsigned short f2bf(float f) {
    union { float f; unsigned int i; } v; v.f = f;
    unsigned int r = v.i + 0x7FFFu + ((v.i >> 16) & 1u);  // round-nearest-even
    return (unsigned short)(r >> 16);
}

// ================= init: counts=0 =================
__global__ void k_init(int* __restrict__ counts, int N) {
    int i = blockIdx.x * blockDim.x + threadIdx.x;
    if (i < N) counts[i] = 0;
}

// ================= in-degree histogram over dst =================
__global__ void k_hist(const int* __restrict__ dst, int* __restrict__ counts, int E) {
    int e = blockIdx.x * blockDim.x + threadIdx.x;
    if (e < E) atomicAdd(&counts[dst[e]], 1);
}

// ================= transpose W1 to col-major [c][k] =================
__global__ void k_wt(const float* __restrict__ W1, float* __restrict__ Wt) {
    int i = blockIdx.x * blockDim.x + threadIdx.x;
    if (i < F0 * F1) {
        int k = i / F1, c = i - k * F1;
        Wt[c * F0 + k] = W1[i];
    }
}

// ================= graph segment boundaries from sorted batch ==============
__global__ void k_gseg(const int* __restrict__ batch, int* __restrict__ gs, int N, int G) {
    int i = blockIdx.x * blockDim.x + threadIdx.x;
    if (i >= N) return;
    int bi = batch[i];
    int bp = (i == 0) ? -1 : batch[i - 1];
    for (int g = bp + 1; g <= bi; g++) gs[g] = i;
    if (i == N - 1) {
        for (int g = bi + 1; g <= G; g++) gs[g] = N;
    }
}

// ================= scan stage A: per-1024-chunk prefix + dinv ===========
__global__ __launch_bounds__(256) void k_scanA(const int* __restrict__ counts,
                                               int* __restrict__ pre,
                                               int* __restrict__ blockSums,
                                               float* __restrict__ dinv, int N) {
    __shared__ int s[256];
    int t = threadIdx.x;
    int base = blockIdx.x * 1024 + t * 4;
    int v[4], sum = 0;
#pragma unroll
    for (int u = 0; u < 4; u++) {
        int idx = base + u;
        v[u] = (idx < N) ? counts[idx] : 0;
        if (idx < N) dinv[idx] = rsqrtf((float)v[u] + 1.0f);  // self loop
        sum += v[u];
    }
    s[t] = sum;
    __syncthreads();
    for (int off = 1; off < 256; off <<= 1) {
        int y = (t >= off) ? s[t - off] : 0;
        __syncthreads();
        s[t] += y;
        __syncthreads();
    }
    int threadExcl = s[t] - sum;
    int run = 0;
#pragma unroll
    for (int u = 0; u < 4; u++) {
        int idx = base + u;
        if (idx < N) pre[idx] = threadExcl + run;
        run += v[u];
    }
    if (t == 255) blockSums[blockIdx.x] = s[255];
}

// ================= scan stage B: exclusive scan of block sums (M<=64) ======
__global__ void k_scanB(int* __restrict__ blockSums, int M) {
    __shared__ int s[64];
    int t = threadIdx.x;
    int own = (t < M) ? blockSums[t] : 0;
    s[t] = own;
    __syncthreads();
    for (int off = 1; off < 64; off <<= 1) {
        int y = (t >= off) ? s[t - off] : 0;
        __syncthreads();
        s[t] += y;
        __syncthreads();
    }
    if (t < M) blockSums[t] = s[t] - own;
}

// ================= scan stage C: add block offsets; emit cursor ============
__global__ void k_scanC(int* __restrict__ row_start, int* __restrict__ cursor,
                        const int* __restrict__ blockSums, int N, int E) {
    int idx = blockIdx.x * blockDim.x + threadIdx.x;
    if (idx < N) {
        int v = row_start[idx] + blockSums[idx >> 10];
        row_start[idx] = v;
        cursor[idx] = v;
    }
    if (idx == 0) row_start[N] = E;
}

// ================= scatter edges into CSR (by dst), src index only =========
__global__ void k_scatter(const int* __restrict__ src, const int* __restrict__ dst,
                          int* __restrict__ cursor, int* __restrict__ ssrc, int E) {
    int e = blockIdx.x * blockDim.x + threadIdx.x;
    if (e >= E) return;
    int s = src[e], d = dst[e];
    int pos = atomicAdd(&cursor[d], 1);
    ssrc[pos] = s;
}

// ================= lin1: h1' = (x @ W1) * dinv[node], bf16 out ============
// one wave = 64 nodes x 17 cols; W (col-major) read wave-uniform -> s_load.
__global__ __launch_bounds__(256) void k_lin1(const float* __restrict__ x,
                                              const float* __restrict__ Wt,
                                              const float* __restrict__ dinv,
                                              unsigned short* __restrict__ h1b, int N) {
    int lane = threadIdx.x & 63;
    int cq   = threadIdx.x >> 6;          // wave id in block: 0..3
    int c0   = cq * 17;
    int node = blockIdx.x * 64 + lane;
    if (node >= N) return;

    int rb[17];
#pragma unroll
    for (int j = 0; j < 17; j++) rb[j] = rfl((c0 + j) * F0);

    float acc[17];
#pragma unroll
    for (int j = 0; j < 17; j++) acc[j] = 0.0f;

    const float* xrow = x + (size_t)node * F0;
    for (int k = 0; k < F0; k += 4) {
        float4 xv = *(const float4*)&xrow[k];
#pragma unroll
        for (int j = 0; j < 17; j++) {
            float4 wv = *(const float4*)&Wt[rb[j] + k];
            acc[j] += xv.x * wv.x + xv.y * wv.y + xv.z * wv.z + xv.w * wv.w;
        }
    }
    float d = dinv[node];
    unsigned short* hrow = h1b + (size_t)node * F1 + c0;
#pragma unroll
    for (int j = 0; j < 17; j++) hrow[j] = f2bf(acc[j] * d);
}

// ================= fused: agg1 gather (bf16, pre-scaled) + bias/relu + @W2 =
// agg1[n] = dinv[n] * (sum_{s in nbr} h1'[s] + h1'[n]);  h2'[n] = (relu(agg1+b1)@W2)*dinv[n]
__global__ __launch_bounds__(256) void k_gather1_lin2(const unsigned short* __restrict__ h1b,
                                                      const float* __restrict__ dinv,
                                                      const int* __restrict__ row_start,
                                                      const int* __restrict__ ssrc,
                                                      const float* __restrict__ b1,
                                                      const float* __restrict__ W2,
                                                      float* __restrict__ h2p, int N) {
    __shared__ float sw2[F1 * F2];
    __shared__ float sb1[F1];
    int tid = threadIdx.x;
    for (int i = tid; i < F1 * F2; i += 256) sw2[i] = W2[i];
    if (tid < F1) sb1[tid] = b1[tid];
    __syncthreads();

    int lane = tid & 63;
    int n = blockIdx.x * 4 + (tid >> 6);
    if (n >= N) return;

    bool hi = lane < (F1 - 64);
    int colhi = 64 + (lane & 3);

    const unsigned short* selfrow = h1b + (size_t)n * F1;
    float acc0 = bf2f(selfrow[lane]);
    float acc1 = hi ? bf2f(selfrow[colhi]) : 0.0f;

    int js = row_start[n], je = row_start[n + 1];
    int j = js;
    for (; j + 3 < je; j += 4) {
        int s0 = rfl(ssrc[j + 0]), s1 = rfl(ssrc[j + 1]);
        int s2 = rfl(ssrc[j + 2]), s3 = rfl(ssrc[j + 3]);
        const unsigned short* r0 = h1b + (size_t)s0 * F1;
        const unsigned short* r1 = h1b + (size_t)s1 * F1;
        const unsigned short* r2 = h1b + (size_t)s2 * F1;
        const unsigned short* r3 = h1b + (size_t)s3 * F1;
        float a0 = bf2f(r0[lane]), a1 = bf2f(r1[lane]);
        float a2 = bf2f(r2[lane]), a3 = bf2f(r3[lane]);
        acc0 += (a0 + a1) + (a2 + a3);
        if (hi) {
            float b0v = bf2f(r0[colhi]), b1v = bf2f(r1[colhi]);
            float b2v = bf2f(r2[colhi]), b3v = bf2f(r3[colhi]);
            acc1 += (b0v + b1v) + (b2v + b3v);
        }
    }
    for (; j < je; j++) {
        int s = rfl(ssrc[j]);
        const unsigned short* r = h1b + (size_t)s * F1;
        acc0 += bf2f(r[lane]);
        if (hi) acc1 += bf2f(r[colhi]);
    }

    float d = dinv[n];
    float v0 = fmaf(acc0, d, sb1[lane]);                 v0 = v0 > 0.0f ? v0 : 0.0f;
    float v1 = hi ? fmaf(acc1, d, sb1[colhi]) : 0.0f;    v1 = v1 > 0.0f ? v1 : 0.0f;

    float p[F2];
#pragma unroll
    for (int c = 0; c < F2; c++)
        p[c] = v0 * sw2[lane * F2 + c] + v1 * sw2[colhi * F2 + c];

#pragma unroll
    for (int off = 1; off < 64; off <<= 1) {
#pragma unroll
        for (int c = 0; c < F2; c++) p[c] += __shfl_xor(p[c], off, 64);
    }
    if (lane == 0) {
#pragma unroll
        for (int c = 0; c < F2; c++) h2p[(size_t)n * F2 + c] = p[c] * d;
    }
}

// ================= gather2 + bias/relu + head -> ynode (NO atomics) ========
// 8 lanes per node; lanes stride over edges; 3-step shfl reduce; lane0 head.
__global__ __launch_bounds__(256) void k_gather2(const float* __restrict__ h2p,
                                                 const float* __restrict__ dinv,
                                                 const int* __restrict__ row_start,
                                                 const int* __restrict__ ssrc,
                                                 const float* __restrict__ b2,
                                                 const float* __restrict__ Wl,
                                                 const float* __restrict__ bl,
                                                 const float* __restrict__ Wl2,
                                                 const float* __restrict__ bl2,
                                                 float* __restrict__ ynode, int N) {
    int t = blockIdx.x * blockDim.x + threadIdx.x;
    int n = t >> 3;
    int l = t & 7;
    if (n >= N) return;

    float acc[F2] = {0, 0, 0, 0, 0, 0};
    if (l == 0) {  // self-loop term h2'[n]
        const float* sr = h2p + (size_t)n * F2;
        float2 p0 = *(const float2*)&sr[0];
        float2 p1 = *(const float2*)&sr[2];
        float2 p2 = *(const float2*)&sr[4];
        acc[0] = p0.x; acc[1] = p0.y;
        acc[2] = p1.x; acc[3] = p1.y;
        acc[4] = p2.x; acc[5] = p2.y;
    }

    int js = row_start[n], je = row_start[n + 1];
    for (int j = js + l; j < je; j += 8) {
        int s = ssrc[j];
        const float* r = h2p + (size_t)s * F2;
        float2 p0 = *(const float2*)&r[0];
        float2 p1 = *(const float2*)&r[2];
        float2 p2 = *(const float2*)&r[4];
        acc[0] += p0.x; acc[1] += p0.y;
        acc[2] += p1.x; acc[3] += p1.y;
        acc[4] += p2.x; acc[5] += p2.y;
    }

#pragma unroll
    for (int off = 1; off < 8; off <<= 1) {
#pragma unroll
        for (int c = 0; c < F2; c++) acc[c] += __shfl_xor(acc[c], off, 8);
    }

    if (l == 0) {
        float d = dinv[n];
        float y = 0.0f;
#pragma unroll
        for (int c = 0; c < F2; c++) {
            float v = fmaf(acc[c], d, b2[c]);
            v = v > 0.0f ? v : 0.0f;
            float we = Wl[c * 3 + 0] * Wl2[0] + Wl[c * 3 + 1] * Wl2[1] + Wl[c * 3 + 2] * Wl2[2];
            y = fmaf(v, we, y);
        }
        float cnst = bl[0] * Wl2[0] + bl[1] * Wl2[1] + bl[2] * Wl2[2] + bl2[0];
        ynode[n] = y + cnst;
    }
}

// ================= pool: one block per graph, tree reduce + sigmoid ========
__global__ __launch_bounds__(256) void k_pool(const float* __restrict__ ynode,
                                              const int* __restrict__ gs,
                                              float* __restrict__ out, int G) {
    int g = blockIdx.x;
    int s0 = gs[g], e0 = gs[g + 1];
    int t = threadIdx.x;
    float a = 0.0f;
    for (int i = s0 + t; i < e0; i += 256) a += ynode[i];
#pragma unroll
    for (int off = 1; off < 64; off <<= 1) a += __shfl_xor(a, off, 64);
    __shared__ float sm[4];
    if ((t & 63) == 0) sm[t >> 6] = a;
    __syncthreads();
    if (t == 0) {
        float tot = sm[0] + sm[1] + sm[2] + sm[3];
        out[g] = 1.0f / (1.0f + expf(-tot));
    }
}

extern "C" void kernel_launch(void* const* d_in, const int* in_sizes, int n_in,
                              void* d_out, int out_size, void* d_ws, size_t ws_size,
                              hipStream_t stream) {
    const float* x     = (const float*)d_in[0];
    const int*   ei    = (const int*)d_in[1];
    const int*   batch = (const int*)d_in[2];
    const float* W1    = (const float*)d_in[3];
    const float* b1    = (const float*)d_in[4];
    const float* W2    = (const float*)d_in[5];
    const float* b2    = (const float*)d_in[6];
    const float* Wl    = (const float*)d_in[7];
    const float* bl    = (const float*)d_in[8];
    const float* Wl2   = (const float*)d_in[9];
    const float* bl2   = (const float*)d_in[10];
    float* out = (float*)d_out;

    int N = in_sizes[0] / F0;   // 50000
    int E = in_sizes[1] / 2;    // 512000
    int G = out_size;           // 512
    const int* src = ei;
    const int* dst = ei + E;

    char* ws = (char*)d_ws;
    size_t off = 0;
    auto alloc = [&](size_t bytes) {
        void* p = ws + off;
        off = (off + bytes + 255) & ~(size_t)255;
        return p;
    };
    int*   counts    = (int*)alloc((size_t)N * 4);        // reused as cursor
    int*   row_start = (int*)alloc((size_t)(N + 1) * 4);
    float* dinv      = (float*)alloc((size_t)N * 4);
    int*   ssrc      = (int*)alloc((size_t)E * 4);
    unsigned short* h1b = (unsigned short*)alloc((size_t)N * F1 * 2);
    float* h2p       = (float*)alloc((size_t)N * F2 * 4);
    float* ynode     = (float*)alloc((size_t)N * 4);
    int*   gs        = (int*)alloc((size_t)(G + 1) * 4);
    int*   blockSums = (int*)alloc(64 * 4);
    float* Wt        = (float*)alloc((size_t)F0 * F1 * 4);

    const int B = 256;
    int nScanBlocks = (N + 1023) / 1024;   // 49

    k_init<<<(N + B - 1) / B, B, 0, stream>>>(counts, N);
    k_hist<<<(E + B - 1) / B, B, 0, stream>>>(dst, counts, E);
    k_wt<<<(F0 * F1 + B - 1) / B, B, 0, stream>>>(W1, Wt);
    k_gseg<<<(N + B - 1) / B, B, 0, stream>>>(batch, gs, N, G);
    k_scanA<<<nScanBlocks, 256, 0, stream>>>(counts, row_start, blockSums, dinv, N);
    k_scanB<<<1, 64, 0, stream>>>(blockSums, nScanBlocks);
    k_scanC<<<(N + B - 1) / B, B, 0, stream>>>(row_start, counts /*cursor*/, blockSums, N, E);
    k_scatter<<<(E + B - 1) / B, B, 0, stream>>>(src, dst, counts /*cursor*/, ssrc, E);
    k_lin1<<<(N + 63) / 64, 256, 0, stream>>>(x, Wt, dinv, h1b, N);
    k_gather1_lin2<<<(N + 3) / 4, 256, 0, stream>>>(h1b, dinv, row_start, ssrc, b1, W2, h2p, N);
    k_gather2<<<((N * 8) + B - 1) / B, B, 0, stream>>>(h2p, dinv, row_start, ssrc,
                                                       b2, Wl, bl, Wl2, bl2, ynode, N);
    k_pool<<<G, 256, 0, stream>>>(ynode, gs, out, G);
}

// Round 6
// 171.643 us; speedup vs baseline: 2.6384x; 1.0097x over previous
//
#include <hip/hip_runtime.h>
#include <math.h>

#define F0 136
#define F1 68
#define F2 6

__device__ inline int rfl(int v) { return __builtin_amdgcn_readfirstlane(v); }

__device__ inline float bf2f(unsigned short u) {
    union { unsigned int i; float f; } v; v.i = ((unsigned int)u) << 16; return v.f;
}
__device__ inline unsigned short f2bf(float f) {
    union { float f; unsigned int i; } v; v.f = f;
    unsigned int r = v.i + 0x7FFFu + ((v.i >> 16) & 1u);  // round-nearest-even
    return (unsigned short)(r >> 16);
}

// ================= init: counts=0 =================
__global__ void k_init(int* __restrict__ counts, int N) {
    int i = blockIdx.x * blockDim.x + threadIdx.x;
    if (i < N) counts[i] = 0;
}

// ================= in-degree histogram over dst =================
__global__ void k_hist(const int* __restrict__ dst, int* __restrict__ counts, int E) {
    int e = blockIdx.x * blockDim.x + threadIdx.x;
    if (e < E) atomicAdd(&counts[dst[e]], 1);
}

// ================= transpose W1 to col-major [c][k] =================
__global__ void k_wt(const float* __restrict__ W1, float* __restrict__ Wt) {
    int i = blockIdx.x * blockDim.x + threadIdx.x;
    if (i < F0 * F1) {
        int k = i / F1, c = i - k * F1;
        Wt[c * F0 + k] = W1[i];
    }
}

// ================= graph segment boundaries from sorted batch ==============
__global__ void k_gseg(const int* __restrict__ batch, int* __restrict__ gs, int N, int G) {
    int i = blockIdx.x * blockDim.x + threadIdx.x;
    if (i >= N) return;
    int bi = batch[i];
    int bp = (i == 0) ? -1 : batch[i - 1];
    for (int g = bp + 1; g <= bi; g++) gs[g] = i;
    if (i == N - 1) {
        for (int g = bi + 1; g <= G; g++) gs[g] = N;
    }
}

// ================= scan stage A: per-1024-chunk prefix + dinv ===========
__global__ __launch_bounds__(256) void k_scanA(const int* __restrict__ counts,
                                               int* __restrict__ pre,
                                               int* __restrict__ blockSums,
                                               float* __restrict__ dinv, int N) {
    __shared__ int s[256];
    int t = threadIdx.x;
    int base = blockIdx.x * 1024 + t * 4;
    int v[4], sum = 0;
#pragma unroll
    for (int u = 0; u < 4; u++) {
        int idx = base + u;
        v[u] = (idx < N) ? counts[idx] : 0;
        if (idx < N) dinv[idx] = rsqrtf((float)v[u] + 1.0f);  // self loop
        sum += v[u];
    }
    s[t] = sum;
    __syncthreads();
    for (int off = 1; off < 256; off <<= 1) {
        int y = (t >= off) ? s[t - off] : 0;
        __syncthreads();
        s[t] += y;
        __syncthreads();
    }
    int threadExcl = s[t] - sum;
    int run = 0;
#pragma unroll
    for (int u = 0; u < 4; u++) {
        int idx = base + u;
        if (idx < N) pre[idx] = threadExcl + run;
        run += v[u];
    }
    if (t == 255) blockSums[blockIdx.x] = s[255];
}

// ================= scan stage B: exclusive scan of block sums (M<=64) ======
__global__ void k_scanB(int* __restrict__ blockSums, int M) {
    __shared__ int s[64];
    int t = threadIdx.x;
    int own = (t < M) ? blockSums[t] : 0;
    s[t] = own;
    __syncthreads();
    for (int off = 1; off < 64; off <<= 1) {
        int y = (t >= off) ? s[t - off] : 0;
        __syncthreads();
        s[t] += y;
        __syncthreads();
    }
    if (t < M) blockSums[t] = s[t] - own;
}

// ================= scan stage C: add block offsets; emit cursor ============
__global__ void k_scanC(int* __restrict__ row_start, int* __restrict__ cursor,
                        const int* __restrict__ blockSums, int N, int E) {
    int idx = blockIdx.x * blockDim.x + threadIdx.x;
    if (idx < N) {
        int v = row_start[idx] + blockSums[idx >> 10];
        row_start[idx] = v;
        cursor[idx] = v;
    }
    if (idx == 0) row_start[N] = E;
}

// ================= scatter edges into CSR (by dst), src index only =========
__global__ void k_scatter(const int* __restrict__ src, const int* __restrict__ dst,
                          int* __restrict__ cursor, int* __restrict__ ssrc, int E) {
    int e = blockIdx.x * blockDim.x + threadIdx.x;
    if (e >= E) return;
    int s = src[e], d = dst[e];
    int pos = atomicAdd(&cursor[d], 1);
    ssrc[pos] = s;
}

// ================= lin1: h1' = (x @ W1) * dinv[node], bf16 out ============
// x tile staged into LDS (coalesced), W via wave-uniform scalar loads.
// wave = 64 nodes x 17 cols; block = 4 waves = 4 col-groups, same 64 nodes.
__global__ __launch_bounds__(256) void k_lin1(const float* __restrict__ x,
                                              const float* __restrict__ Wt,
                                              const float* __restrict__ dinv,
                                              unsigned short* __restrict__ h1b, int N) {
    __shared__ float xs[64 * 137];   // stride 137: gcd(137%32=9,32)=1 -> conflict-free
    int tid = threadIdx.x;
    int base = blockIdx.x * 64;

    // ---- coalesced stage: 8704 floats via float4 ----
    const float* xsrc = x + (size_t)base * F0;
    long limit = ((long)N - base) * F0;
    if (limit > 64 * F0) limit = 64 * F0;
    for (int i = tid * 4; i < 64 * F0; i += 256 * 4) {
        float4 v = make_float4(0.f, 0.f, 0.f, 0.f);
        if (i + 3 < limit) {
            v = *(const float4*)&xsrc[i];
        } else {
            if (i + 0 < limit) v.x = xsrc[i + 0];
            if (i + 1 < limit) v.y = xsrc[i + 1];
            if (i + 2 < limit) v.z = xsrc[i + 2];
            if (i + 3 < limit) v.w = xsrc[i + 3];
        }
        int node = i / F0, k = i - node * F0;
        *(float4*)&xs[node * 137 + k] = v;
    }
    __syncthreads();

    int lane = tid & 63;
    int wv   = tid >> 6;
    int c0   = wv * 17;
    int node = base + lane;

    int rb[17];
#pragma unroll
    for (int j = 0; j < 17; j++) rb[j] = rfl((c0 + j) * F0);

    float acc[17];
#pragma unroll
    for (int j = 0; j < 17; j++) acc[j] = 0.0f;

    const float* xrow = &xs[lane * 137];
    for (int k = 0; k < F0; k += 4) {
        float4 xv = *(const float4*)&xrow[k];
#pragma unroll
        for (int j = 0; j < 17; j++) {
            float4 wvv = *(const float4*)&Wt[rb[j] + k];
            acc[j] += xv.x * wvv.x + xv.y * wvv.y + xv.z * wvv.z + xv.w * wvv.w;
        }
    }
    if (node < N) {
        float d = dinv[node];
        unsigned short* hrow = h1b + (size_t)node * F1 + c0;
#pragma unroll
        for (int j = 0; j < 17; j++) hrow[j] = f2bf(acc[j] * d);
    }
}

// ================= fused: agg1 gather (bf16, pre-scaled) + bias/relu + @W2 =
// one wave per node; lane l covers col l (lanes 0..3 also col 64+l); unroll x8
__global__ __launch_bounds__(256) void k_gather1_lin2(const unsigned short* __restrict__ h1b,
                                                      const float* __restrict__ dinv,
                                                      const int* __restrict__ row_start,
                                                      const int* __restrict__ ssrc,
                                                      const float* __restrict__ b1,
                                                      const float* __restrict__ W2,
                                                      float* __restrict__ h2p, int N) {
    __shared__ float sw2[F1 * F2];
    __shared__ float sb1[F1];
    int tid = threadIdx.x;
    for (int i = tid; i < F1 * F2; i += 256) sw2[i] = W2[i];
    if (tid < F1) sb1[tid] = b1[tid];
    __syncthreads();

    int lane = tid & 63;
    int n = blockIdx.x * 4 + (tid >> 6);
    if (n >= N) return;

    bool hi = lane < (F1 - 64);
    int colhi = 64 + (lane & 3);

    const unsigned short* selfrow = h1b + (size_t)n * F1;
    float acc0 = bf2f(selfrow[lane]);
    float acc1 = hi ? bf2f(selfrow[colhi]) : 0.0f;

    int js = row_start[n], je = row_start[n + 1];
    int j = js;
    for (; j + 7 < je; j += 8) {
        const unsigned short* r[8];
#pragma unroll
        for (int u = 0; u < 8; u++) r[u] = h1b + (size_t)rfl(ssrc[j + u]) * F1;
        float a[8];
#pragma unroll
        for (int u = 0; u < 8; u++) a[u] = bf2f(r[u][lane]);
#pragma unroll
        for (int u = 0; u < 8; u++) acc0 += a[u];
        if (hi) {
            float b[8];
#pragma unroll
            for (int u = 0; u < 8; u++) b[u] = bf2f(r[u][colhi]);
#pragma unroll
            for (int u = 0; u < 8; u++) acc1 += b[u];
        }
    }
    for (; j + 3 < je; j += 4) {
        const unsigned short* r[4];
#pragma unroll
        for (int u = 0; u < 4; u++) r[u] = h1b + (size_t)rfl(ssrc[j + u]) * F1;
#pragma unroll
        for (int u = 0; u < 4; u++) acc0 += bf2f(r[u][lane]);
        if (hi) {
#pragma unroll
            for (int u = 0; u < 4; u++) acc1 += bf2f(r[u][colhi]);
        }
    }
    for (; j < je; j++) {
        int s = rfl(ssrc[j]);
        const unsigned short* r = h1b + (size_t)s * F1;
        acc0 += bf2f(r[lane]);
        if (hi) acc1 += bf2f(r[colhi]);
    }

    float d = dinv[n];
    float v0 = fmaf(acc0, d, sb1[lane]);                 v0 = v0 > 0.0f ? v0 : 0.0f;
    float v1 = hi ? fmaf(acc1, d, sb1[colhi]) : 0.0f;    v1 = v1 > 0.0f ? v1 : 0.0f;

    float p[F2];
#pragma unroll
    for (int c = 0; c < F2; c++)
        p[c] = v0 * sw2[lane * F2 + c] + v1 * sw2[colhi * F2 + c];

#pragma unroll
    for (int off = 1; off < 64; off <<= 1) {
#pragma unroll
        for (int c = 0; c < F2; c++) p[c] += __shfl_xor(p[c], off, 64);
    }
    if (lane == 0) {
#pragma unroll
        for (int c = 0; c < F2; c++) h2p[(size_t)n * F2 + c] = p[c] * d;
    }
}

// ================= gather2 + bias/relu + head -> ynode (NO atomics) ========
__global__ __launch_bounds__(256) void k_gather2(const float* __restrict__ h2p,
                                                 const float* __restrict__ dinv,
                                                 const int* __restrict__ row_start,
                                                 const int* __restrict__ ssrc,
                                                 const float* __restrict__ b2,
                                                 const float* __restrict__ Wl,
                                                 const float* __restrict__ bl,
                                                 const float* __restrict__ Wl2,
                                                 const float* __restrict__ bl2,
                                                 float* __restrict__ ynode, int N) {
    int t = blockIdx.x * blockDim.x + threadIdx.x;
    int n = t >> 3;
    int l = t & 7;
    if (n >= N) return;

    float acc[F2] = {0, 0, 0, 0, 0, 0};
    if (l == 0) {  // self-loop term h2'[n]
        const float* sr = h2p + (size_t)n * F2;
        float2 p0 = *(const float2*)&sr[0];
        float2 p1 = *(const float2*)&sr[2];
        float2 p2 = *(const float2*)&sr[4];
        acc[0] = p0.x; acc[1] = p0.y;
        acc[2] = p1.x; acc[3] = p1.y;
        acc[4] = p2.x; acc[5] = p2.y;
    }

    int js = row_start[n], je = row_start[n + 1];
    for (int j = js + l; j < je; j += 8) {
        int s = ssrc[j];
        const float* r = h2p + (size_t)s * F2;
        float2 p0 = *(const float2*)&r[0];
        float2 p1 = *(const float2*)&r[2];
        float2 p2 = *(const float2*)&r[4];
        acc[0] += p0.x; acc[1] += p0.y;
        acc[2] += p1.x; acc[3] += p1.y;
        acc[4] += p2.x; acc[5] += p2.y;
    }

#pragma unroll
    for (int off = 1; off < 8; off <<= 1) {
#pragma unroll
        for (int c = 0; c < F2; c++) acc[c] += __shfl_xor(acc[c], off, 8);
    }

    if (l == 0) {
        float d = dinv[n];
        float y = 0.0f;
#pragma unroll
        for (int c = 0; c < F2; c++) {
            float v = fmaf(acc[c], d, b2[c]);
            v = v > 0.0f ? v : 0.0f;
            float we = Wl[c * 3 + 0] * Wl2[0] + Wl[c * 3 + 1] * Wl2[1] + Wl[c * 3 + 2] * Wl2[2];
            y = fmaf(v, we, y);
        }
        float cnst = bl[0] * Wl2[0] + bl[1] * Wl2[1] + bl[2] * Wl2[2] + bl2[0];
        ynode[n] = y + cnst;
    }
}

// ================= pool: one block per graph, tree reduce + sigmoid ========
__global__ __launch_bounds__(256) void k_pool(const float* __restrict__ ynode,
                                              const int* __restrict__ gs,
                                              float* __restrict__ out, int G) {
    int g = blockIdx.x;
    int s0 = gs[g], e0 = gs[g + 1];
    int t = threadIdx.x;
    float a = 0.0f;
    for (int i = s0 + t; i < e0; i += 256) a += ynode[i];
#pragma unroll
    for (int off = 1; off < 64; off <<= 1) a += __shfl_xor(a, off, 64);
    __shared__ float sm[4];
    if ((t & 63) == 0) sm[t >> 6] = a;
    __syncthreads();
    if (t == 0) {
        float tot = sm[0] + sm[1] + sm[2] + sm[3];
        out[g] = 1.0f / (1.0f + expf(-tot));
    }
}

extern "C" void kernel_launch(void* const* d_in, const int* in_sizes, int n_in,
                              void* d_out, int out_size, void* d_ws, size_t ws_size,
                              hipStream_t stream) {
    const float* x     = (const float*)d_in[0];
    const int*   ei    = (const int*)d_in[1];
    const int*   batch = (const int*)d_in[2];
    const float* W1    = (const float*)d_in[3];
    const float* b1    = (const float*)d_in[4];
    const float* W2    = (const float*)d_in[5];
    const float* b2    = (const float*)d_in[6];
    const float* Wl    = (const float*)d_in[7];
    const float* bl    = (const float*)d_in[8];
    const float* Wl2   = (const float*)d_in[9];
    const float* bl2   = (const float*)d_in[10];
    float* out = (float*)d_out;

    int N = in_sizes[0] / F0;   // 50000
    int E = in_sizes[1] / 2;    // 512000
    int G = out_size;           // 512
    const int* src = ei;
    const int* dst = ei + E;

    char* ws = (char*)d_ws;
    size_t off = 0;
    auto alloc = [&](size_t bytes) {
        void* p = ws + off;
        off = (off + bytes + 255) & ~(size_t)255;
        return p;
    };
    int*   counts    = (int*)alloc((size_t)N * 4);        // reused as cursor
    int*   row_start = (int*)alloc((size_t)(N + 1) * 4);
    float* dinv      = (float*)alloc((size_t)N * 4);
    int*   ssrc      = (int*)alloc((size_t)E * 4);
    unsigned short* h1b = (unsigned short*)alloc((size_t)N * F1 * 2);
    float* h2p       = (float*)alloc((size_t)N * F2 * 4);
    float* ynode     = (float*)alloc((size_t)N * 4);
    int*   gs        = (int*)alloc((size_t)(G + 1) * 4);
    int*   blockSums = (int*)alloc(64 * 4);
    float* Wt        = (float*)alloc((size_t)F0 * F1 * 4);

    const int B = 256;
    int nScanBlocks = (N + 1023) / 1024;   // 49

    k_init<<<(N + B - 1) / B, B, 0, stream>>>(counts, N);
    k_hist<<<(E + B - 1) / B, B, 0, stream>>>(dst, counts, E);
    k_wt<<<(F0 * F1 + B - 1) / B, B, 0, stream>>>(W1, Wt);
    k_gseg<<<(N + B - 1) / B, B, 0, stream>>>(batch, gs, N, G);
    k_scanA<<<nScanBlocks, 256, 0, stream>>>(counts, row_start, blockSums, dinv, N);
    k_scanB<<<1, 64, 0, stream>>>(blockSums, nScanBlocks);
    k_scanC<<<(N + B - 1) / B, B, 0, stream>>>(row_start, counts /*cursor*/, blockSums, N, E);
    k_scatter<<<(E + B - 1) / B, B, 0, stream>>>(src, dst, counts /*cursor*/, ssrc, E);
    k_lin1<<<(N + 63) / 64, 256, 0, stream>>>(x, Wt, dinv, h1b, N);
    k_gather1_lin2<<<(N + 3) / 4, 256, 0, stream>>>(h1b, dinv, row_start, ssrc, b1, W2, h2p, N);
    k_gather2<<<((N * 8) + B - 1) / B, B, 0, stream>>>(h2p, dinv, row_start, ssrc,
                                                       b2, Wl, bl, Wl2, bl2, ynode, N);
    k_pool<<<G, 256, 0, stream>>>(ynode, gs, out, G);
}

// Round 7
// 135.032 us; speedup vs baseline: 3.3538x; 1.2711x over previous
//
#include <hip/hip_runtime.h>
#include <math.h>

#define F0 136
#define F1 68
#define F2 6
#define KP 160   // K padded to 5*32
#define NP 80    // N padded to 5*16

typedef __attribute__((ext_vector_type(8))) short short8v;
typedef __attribute__((ext_vector_type(4))) float f32x4;

__device__ inline int rfl(int v) { return __builtin_amdgcn_readfirstlane(v); }

__device__ inline float bf2f(unsigned short u) {
    union { unsigned int i; float f; } v; v.i = ((unsigned int)u) << 16; return v.f;
}
__device__ inline unsigned short f2bf(float f) {
    union { float f; unsigned int i; } v; v.f = f;
    unsigned int r = v.i + 0x7FFFu + ((v.i >> 16) & 1u);  // round-nearest-even
    return (unsigned short)(r >> 16);
}

// ================= init: counts=0 =================
__global__ void k_init(int* __restrict__ counts, int N) {
    int i = blockIdx.x * blockDim.x + threadIdx.x;
    if (i < N) counts[i] = 0;
}

// ================= in-degree histogram over dst =================
__global__ void k_hist(const int* __restrict__ dst, int* __restrict__ counts, int E) {
    int e = blockIdx.x * blockDim.x + threadIdx.x;
    if (e < E) atomicAdd(&counts[dst[e]], 1);
}

// ========= W1 -> bf16 col-major [NP][KP], zero-padded =========
__global__ void k_wcvt(const float* __restrict__ W1, unsigned short* __restrict__ Wb) {
    int i = blockIdx.x * blockDim.x + threadIdx.x;
    if (i >= NP * KP) return;
    int c = i / KP, k = i - c * KP;
    float v = (c < F1 && k < F0) ? W1[k * F1 + c] : 0.0f;
    Wb[c * KP + k] = f2bf(v);
}

// ================= graph segment boundaries from sorted batch ==============
__global__ void k_gseg(const int* __restrict__ batch, int* __restrict__ gs, int N, int G) {
    int i = blockIdx.x * blockDim.x + threadIdx.x;
    if (i >= N) return;
    int bi = batch[i];
    int bp = (i == 0) ? -1 : batch[i - 1];
    for (int g = bp + 1; g <= bi; g++) gs[g] = i;
    if (i == N - 1) {
        for (int g = bi + 1; g <= G; g++) gs[g] = N;
    }
}

// ================= scan stage A: per-1024-chunk prefix + dinv ===========
__global__ __launch_bounds__(256) void k_scanA(const int* __restrict__ counts,
                                               int* __restrict__ pre,
                                               int* __restrict__ blockSums,
                                               float* __restrict__ dinv, int N) {
    __shared__ int s[256];
    int t = threadIdx.x;
    int base = blockIdx.x * 1024 + t * 4;
    int v[4], sum = 0;
#pragma unroll
    for (int u = 0; u < 4; u++) {
        int idx = base + u;
        v[u] = (idx < N) ? counts[idx] : 0;
        if (idx < N) dinv[idx] = rsqrtf((float)v[u] + 1.0f);  // self loop
        sum += v[u];
    }
    s[t] = sum;
    __syncthreads();
    for (int off = 1; off < 256; off <<= 1) {
        int y = (t >= off) ? s[t - off] : 0;
        __syncthreads();
        s[t] += y;
        __syncthreads();
    }
    int threadExcl = s[t] - sum;
    int run = 0;
#pragma unroll
    for (int u = 0; u < 4; u++) {
        int idx = base + u;
        if (idx < N) pre[idx] = threadExcl + run;
        run += v[u];
    }
    if (t == 255) blockSums[blockIdx.x] = s[255];
}

// ================= scan stage B: exclusive scan of block sums (M<=64) ======
__global__ void k_scanB(int* __restrict__ blockSums, int M) {
    __shared__ int s[64];
    int t = threadIdx.x;
    int own = (t < M) ? blockSums[t] : 0;
    s[t] = own;
    __syncthreads();
    for (int off = 1; off < 64; off <<= 1) {
        int y = (t >= off) ? s[t - off] : 0;
        __syncthreads();
        s[t] += y;
        __syncthreads();
    }
    if (t < M) blockSums[t] = s[t] - own;
}

// ================= scan stage C: add block offsets; emit cursor ============
__global__ void k_scanC(int* __restrict__ row_start, int* __restrict__ cursor,
                        const int* __restrict__ blockSums, int N, int E) {
    int idx = blockIdx.x * blockDim.x + threadIdx.x;
    if (idx < N) {
        int v = row_start[idx] + blockSums[idx >> 10];
        row_start[idx] = v;
        cursor[idx] = v;
    }
    if (idx == 0) row_start[N] = E;
}

// ================= scatter edges into CSR (by dst), src index only =========
__global__ void k_scatter(const int* __restrict__ src, const int* __restrict__ dst,
                          int* __restrict__ cursor, int* __restrict__ ssrc, int E) {
    int e = blockIdx.x * blockDim.x + threadIdx.x;
    if (e >= E) return;
    int s = src[e], d = dst[e];
    int pos = atomicAdd(&cursor[d], 1);
    ssrc[pos] = s;
}

// ========== lin1 via MFMA: h1' = (x @ W1) * dinv, bf16 out ==========
// block = 4 waves; wave w owns rows [base+16w, base+16w+16).
// A frag: lane(row=l&15, kgrp=l>>4) reads x[row][k0..k0+7] fp32 -> bf16.
// B frag: lane(col=l&15) reads Wb[col][k0..k0+7] (bf16 col-major, padded).
// D: col = lane&15, row = (lane>>4)*4 + j.
__global__ __launch_bounds__(256) void k_lin1(const float* __restrict__ x,
                                              const unsigned short* __restrict__ Wb,
                                              const float* __restrict__ dinv,
                                              unsigned short* __restrict__ h1b, int N) {
    int tid  = threadIdx.x;
    int lane = tid & 63;
    int w    = tid >> 6;
    int rl   = lane & 15;
    int kg   = lane >> 4;
    int base = blockIdx.x * 64 + w * 16;
    int node = base + rl;
    int nodeClamp = node < N ? node : (N - 1);

    f32x4 acc[5];
#pragma unroll
    for (int t = 0; t < 5; t++) acc[t] = (f32x4){0.f, 0.f, 0.f, 0.f};

#pragma unroll
    for (int kt = 0; kt < 5; kt++) {
        int k0 = kt * 32 + kg * 8;
        short8v a;
        if (k0 < F0) {  // kt<4 always; kt==4 only kg==0 (k 128..135)
            const float* xr = x + (size_t)nodeClamp * F0 + k0;
            float4 lo = *(const float4*)xr;
            float4 hi = *(const float4*)(xr + 4);
            a[0] = (short)f2bf(lo.x); a[1] = (short)f2bf(lo.y);
            a[2] = (short)f2bf(lo.z); a[3] = (short)f2bf(lo.w);
            a[4] = (short)f2bf(hi.x); a[5] = (short)f2bf(hi.y);
            a[6] = (short)f2bf(hi.z); a[7] = (short)f2bf(hi.w);
        } else {
            a = (short8v){0, 0, 0, 0, 0, 0, 0, 0};
        }
#pragma unroll
        for (int nt = 0; nt < 5; nt++) {
            int col = nt * 16 + rl;
            short8v b = *(const short8v*)&Wb[col * KP + k0];
            acc[nt] = __builtin_amdgcn_mfma_f32_16x16x32_bf16(a, b, acc[nt], 0, 0, 0);
        }
    }

    int orow0 = base + kg * 4;
    float dv[4];
#pragma unroll
    for (int j = 0; j < 4; j++) {
        int nr = orow0 + j;
        dv[j] = (nr < N) ? dinv[nr] : 0.0f;
    }
#pragma unroll
    for (int nt = 0; nt < 5; nt++) {
        int col = nt * 16 + rl;
        if (col < F1) {
#pragma unroll
            for (int j = 0; j < 4; j++) {
                int nr = orow0 + j;
                if (nr < N) h1b[(size_t)nr * F1 + col] = f2bf(acc[nt][j] * dv[j]);
            }
        }
    }
}

// ================= fused: agg1 gather (bf16, pre-scaled) + bias/relu + @W2 =
// one wave per node; lane l covers col l (lanes 0..3 also col 64+l); unroll x8
__global__ __launch_bounds__(256) void k_gather1_lin2(const unsigned short* __restrict__ h1b,
                                                      const float* __restrict__ dinv,
                                                      const int* __restrict__ row_start,
                                                      const int* __restrict__ ssrc,
                                                      const float* __restrict__ b1,
                                                      const float* __restrict__ W2,
                                                      float* __restrict__ h2p, int N) {
    __shared__ float sw2[F1 * F2];
    __shared__ float sb1[F1];
    int tid = threadIdx.x;
    for (int i = tid; i < F1 * F2; i += 256) sw2[i] = W2[i];
    if (tid < F1) sb1[tid] = b1[tid];
    __syncthreads();

    int lane = tid & 63;
    int n = blockIdx.x * 4 + (tid >> 6);
    if (n >= N) return;

    bool hi = lane < (F1 - 64);
    int colhi = 64 + (lane & 3);

    const unsigned short* selfrow = h1b + (size_t)n * F1;
    float acc0 = bf2f(selfrow[lane]);
    float acc1 = hi ? bf2f(selfrow[colhi]) : 0.0f;

    int js = row_start[n], je = row_start[n + 1];
    int j = js;
    for (; j + 7 < je; j += 8) {
        const unsigned short* r[8];
#pragma unroll
        for (int u = 0; u < 8; u++) r[u] = h1b + (size_t)rfl(ssrc[j + u]) * F1;
        float a[8];
#pragma unroll
        for (int u = 0; u < 8; u++) a[u] = bf2f(r[u][lane]);
#pragma unroll
        for (int u = 0; u < 8; u++) acc0 += a[u];
        if (hi) {
            float b[8];
#pragma unroll
            for (int u = 0; u < 8; u++) b[u] = bf2f(r[u][colhi]);
#pragma unroll
            for (int u = 0; u < 8; u++) acc1 += b[u];
        }
    }
    for (; j + 3 < je; j += 4) {
        const unsigned short* r[4];
#pragma unroll
        for (int u = 0; u < 4; u++) r[u] = h1b + (size_t)rfl(ssrc[j + u]) * F1;
#pragma unroll
        for (int u = 0; u < 4; u++) acc0 += bf2f(r[u][lane]);
        if (hi) {
#pragma unroll
            for (int u = 0; u < 4; u++) acc1 += bf2f(r[u][colhi]);
        }
    }
    for (; j < je; j++) {
        int s = rfl(ssrc[j]);
        const unsigned short* r = h1b + (size_t)s * F1;
        acc0 += bf2f(r[lane]);
        if (hi) acc1 += bf2f(r[colhi]);
    }

    float d = dinv[n];
    float v0 = fmaf(acc0, d, sb1[lane]);                 v0 = v0 > 0.0f ? v0 : 0.0f;
    float v1 = hi ? fmaf(acc1, d, sb1[colhi]) : 0.0f;    v1 = v1 > 0.0f ? v1 : 0.0f;

    float p[F2];
#pragma unroll
    for (int c = 0; c < F2; c++)
        p[c] = v0 * sw2[lane * F2 + c] + v1 * sw2[colhi * F2 + c];

#pragma unroll
    for (int off = 1; off < 64; off <<= 1) {
#pragma unroll
        for (int c = 0; c < F2; c++) p[c] += __shfl_xor(p[c], off, 64);
    }
    if (lane == 0) {
#pragma unroll
        for (int c = 0; c < F2; c++) h2p[(size_t)n * F2 + c] = p[c] * d;
    }
}

// ================= gather2 + bias/relu + head -> ynode (NO atomics) ========
__global__ __launch_bounds__(256) void k_gather2(const float* __restrict__ h2p,
                                                 const float* __restrict__ dinv,
                                                 const int* __restrict__ row_start,
                                                 const int* __restrict__ ssrc,
                                                 const float* __restrict__ b2,
                                                 const float* __restrict__ Wl,
                                                 const float* __restrict__ bl,
                                                 const float* __restrict__ Wl2,
                                                 const float* __restrict__ bl2,
                                                 float* __restrict__ ynode, int N) {
    int t = blockIdx.x * blockDim.x + threadIdx.x;
    int n = t >> 3;
    int l = t & 7;
    if (n >= N) return;

    float acc[F2] = {0, 0, 0, 0, 0, 0};
    if (l == 0) {  // self-loop term h2'[n]
        const float* sr = h2p + (size_t)n * F2;
        float2 p0 = *(const float2*)&sr[0];
        float2 p1 = *(const float2*)&sr[2];
        float2 p2 = *(const float2*)&sr[4];
        acc[0] = p0.x; acc[1] = p0.y;
        acc[2] = p1.x; acc[3] = p1.y;
        acc[4] = p2.x; acc[5] = p2.y;
    }

    int js = row_start[n], je = row_start[n + 1];
    for (int j = js + l; j < je; j += 8) {
        int s = ssrc[j];
        const float* r = h2p + (size_t)s * F2;
        float2 p0 = *(const float2*)&r[0];
        float2 p1 = *(const float2*)&r[2];
        float2 p2 = *(const float2*)&r[4];
        acc[0] += p0.x; acc[1] += p0.y;
        acc[2] += p1.x; acc[3] += p1.y;
        acc[4] += p2.x; acc[5] += p2.y;
    }

#pragma unroll
    for (int off = 1; off < 8; off <<= 1) {
#pragma unroll
        for (int c = 0; c < F2; c++) acc[c] += __shfl_xor(acc[c], off, 8);
    }

    if (l == 0) {
        float d = dinv[n];
        float y = 0.0f;
#pragma unroll
        for (int c = 0; c < F2; c++) {
            float v = fmaf(acc[c], d, b2[c]);
            v = v > 0.0f ? v : 0.0f;
            float we = Wl[c * 3 + 0] * Wl2[0] + Wl[c * 3 + 1] * Wl2[1] + Wl[c * 3 + 2] * Wl2[2];
            y = fmaf(v, we, y);
        }
        float cnst = bl[0] * Wl2[0] + bl[1] * Wl2[1] + bl[2] * Wl2[2] + bl2[0];
        ynode[n] = y + cnst;
    }
}

// ================= pool: one block per graph, tree reduce + sigmoid ========
__global__ __launch_bounds__(256) void k_pool(const float* __restrict__ ynode,
                                              const int* __restrict__ gs,
                                              float* __restrict__ out, int G) {
    int g = blockIdx.x;
    int s0 = gs[g], e0 = gs[g + 1];
    int t = threadIdx.x;
    float a = 0.0f;
    for (int i = s0 + t; i < e0; i += 256) a += ynode[i];
#pragma unroll
    for (int off = 1; off < 64; off <<= 1) a += __shfl_xor(a, off, 64);
    __shared__ float sm[4];
    if ((t & 63) == 0) sm[t >> 6] = a;
    __syncthreads();
    if (t == 0) {
        float tot = sm[0] + sm[1] + sm[2] + sm[3];
        out[g] = 1.0f / (1.0f + expf(-tot));
    }
}

extern "C" void kernel_launch(void* const* d_in, const int* in_sizes, int n_in,
                              void* d_out, int out_size, void* d_ws, size_t ws_size,
                              hipStream_t stream) {
    const float* x     = (const float*)d_in[0];
    const int*   ei    = (const int*)d_in[1];
    const int*   batch = (const int*)d_in[2];
    const float* W1    = (const float*)d_in[3];
    const float* b1    = (const float*)d_in[4];
    const float* W2    = (const float*)d_in[5];
    const float* b2    = (const float*)d_in[6];
    const float* Wl    = (const float*)d_in[7];
    const float* bl    = (const float*)d_in[8];
    const float* Wl2   = (const float*)d_in[9];
    const float* bl2   = (const float*)d_in[10];
    float* out = (float*)d_out;

    int N = in_sizes[0] / F0;   // 50000
    int E = in_sizes[1] / 2;    // 512000
    int G = out_size;           // 512
    const int* src = ei;
    const int* dst = ei + E;

    char* ws = (char*)d_ws;
    size_t off = 0;
    auto alloc = [&](size_t bytes) {
        void* p = ws + off;
        off = (off + bytes + 255) & ~(size_t)255;
        return p;
    };
    int*   counts    = (int*)alloc((size_t)N * 4);        // reused as cursor
    int*   row_start = (int*)alloc((size_t)(N + 1) * 4);
    float* dinv      = (float*)alloc((size_t)N * 4);
    int*   ssrc      = (int*)alloc((size_t)E * 4);
    unsigned short* h1b = (unsigned short*)alloc((size_t)N * F1 * 2);
    float* h2p       = (float*)alloc((size_t)N * F2 * 4);
    float* ynode     = (float*)alloc((size_t)N * 4);
    int*   gs        = (int*)alloc((size_t)(G + 1) * 4);
    int*   blockSums = (int*)alloc(64 * 4);
    unsigned short* Wb = (unsigned short*)alloc((size_t)NP * KP * 2);

    const int B = 256;
    int nScanBlocks = (N + 1023) / 1024;   // 49

    k_init<<<(N + B - 1) / B, B, 0, stream>>>(counts, N);
    k_hist<<<(E + B - 1) / B, B, 0, stream>>>(dst, counts, E);
    k_wcvt<<<(NP * KP + B - 1) / B, B, 0, stream>>>(W1, Wb);
    k_gseg<<<(N + B - 1) / B, B, 0, stream>>>(batch, gs, N, G);
    k_scanA<<<nScanBlocks, 256, 0, stream>>>(counts, row_start, blockSums, dinv, N);
    k_scanB<<<1, 64, 0, stream>>>(blockSums, nScanBlocks);
    k_scanC<<<(N + B - 1) / B, B, 0, stream>>>(row_start, counts /*cursor*/, blockSums, N, E);
    k_scatter<<<(E + B - 1) / B, B, 0, stream>>>(src, dst, counts /*cursor*/, ssrc, E);
    k_lin1<<<(N + 63) / 64, 256, 0, stream>>>(x, Wb, dinv, h1b, N);
    k_gather1_lin2<<<(N + 3) / 4, 256, 0, stream>>>(h1b, dinv, row_start, ssrc, b1, W2, h2p, N);
    k_gather2<<<((N * 8) + B - 1) / B, B, 0, stream>>>(h2p, dinv, row_start, ssrc,
                                                       b2, Wl, bl, Wl2, bl2, ynode, N);
    k_pool<<<G, 256, 0, stream>>>(ynode, gs, out, G);
}